// Round 8
// baseline (103.556 us; speedup 1.0000x reference)
//
#include <hip/hip_runtime.h>

typedef unsigned short u16;
typedef __bf16 bf16x8 __attribute__((ext_vector_type(8)));
typedef float f32x4 __attribute__((ext_vector_type(4)));
typedef u16 u16x8 __attribute__((ext_vector_type(8)));

#define OSPLIT 8             // oproj K-splits (512 each, 8 steps of 64)
#define SCALE_Q 0.08838834764831843f   // 1/sqrt(128), folded into q

__device__ __forceinline__ u16 f2bf(float f) {
    unsigned u = __builtin_bit_cast(unsigned, f);
    u += 0x7fff + ((u >> 16) & 1);     // RNE
    return (u16)(u >> 16);
}
__device__ __forceinline__ float bf2f(u16 h) {
    unsigned u = ((unsigned)h) << 16;
    return __builtin_bit_cast(float, u);
}
__device__ __forceinline__ f32x4 mfma16(bf16x8 a, bf16x8 b, f32x4 c) {
    return __builtin_amdgcn_mfma_f32_16x16x32_bf16(a, b, c, 0, 0, 0);
}

// ------ Kernel 0: pre-pack c=[x_ctx;x] as bf16 MFMA A-fragments (1 MB) ------
__global__ __launch_bounds__(256)
void k_prep(const float* __restrict__ x, const float* __restrict__ xctx,
            u16* __restrict__ fragA)
{
    int tid = blockIdx.x * 256 + threadIdx.x;   // 65536 threads
    int row = tid >> 9;                         // 0..127
    int kc = tid & 511;                         // k-chunk of 8
    int k0 = kc << 3;
    const float* src = (row < 64) ? (xctx + (size_t)row * 4096)
                                  : (x + (size_t)(row - 64) * 4096);
    f32x4 v0 = *(const f32x4*)&src[k0];
    f32x4 v1 = *(const f32x4*)&src[k0 + 4];
    u16x8 o;
    o[0] = f2bf(v0[0]); o[1] = f2bf(v0[1]); o[2] = f2bf(v0[2]); o[3] = f2bf(v0[3]);
    o[4] = f2bf(v1[0]); o[5] = f2bf(v1[1]); o[6] = f2bf(v1[2]); o[7] = f2bf(v1[3]);
    int ks32 = k0 >> 5;
    int lg = (k0 >> 3) & 3;
    int rt = row >> 4;
    int l = lg * 16 + (row & 15);
    *(u16x8*)&fragA[(((size_t)ks32 * 8 + rt) * 64 + l) * 8] = o;
}

// ---------------- Kernel 1: QKV projection, split-K streaming ---------------
template<int KS>
__global__ __launch_bounds__(256)
void k_qkv(const u16* __restrict__ fragA,
           const float* __restrict__ Wq, const float* __restrict__ Wk,
           const float* __restrict__ Wv, float* __restrict__ part)
{
    constexpr int KCk = 4096 / KS;
    constexpr int NKTk = KCk / 64;
    const int col0 = blockIdx.x * 32;
    const int ksp = blockIdx.y;
    const int ks0 = ksp * KCk;
    const float* W; int ldw, cbase, mat;
    if (col0 < 4096)      { W = Wq; ldw = 4096; cbase = col0;        mat = 0; }
    else if (col0 < 5120) { W = Wk; ldw = 1024; cbase = col0 - 4096; mat = 1; }
    else                  { W = Wv; ldw = 1024; cbase = col0 - 5120; mat = 2; }
    const bool full = (mat != 0);          // k/v need all 128 rows; q only x rows
    const int rowbase = full ? 0 : 64;

    __shared__ __align__(16) u16 Bs[32 * 64];   // [n][k] with XOR swizzle, 4KB

    const int t = threadIdx.x;
    const int w = t >> 6, l = t & 63;
    const int lm = l & 15, lg = l >> 4;

    const int bk = (t >> 3) << 1;          // even k index (k-pair)
    const int bn4 = (t & 7) << 2;          // col group of 4

    f32x4 pb[2];
    f32x4 acc[2][2] = {};

    const int rt0 = full ? (w * 2) : (4 + w);  // A row-tile(s) for this wave

    #define QKV_BLOAD(kt_)                                                     \
    {                                                                          \
        const int kg = ks0 + (kt_) * 64;                                       \
        pb[0] = *(const f32x4*)&W[(size_t)(kg + bk) * ldw + cbase + bn4];      \
        pb[1] = *(const f32x4*)&W[(size_t)(kg + bk + 1) * ldw + cbase + bn4];  \
    }

    #define QKV_BSTORE()                                                       \
    {                                                                          \
        _Pragma("unroll")                                                      \
        for (int j = 0; j < 4; j++) {                                          \
            int n = bn4 + j;                                                   \
            int idx = n * 64 + (bk ^ (((n >> 1) & 7) << 3));                   \
            ushort2 v2; v2.x = f2bf(pb[0][j]); v2.y = f2bf(pb[1][j]);          \
            *(ushort2*)&Bs[idx] = v2;                                          \
        }                                                                      \
    }

    QKV_BLOAD(0);
    #pragma unroll 1
    for (int kt = 0; kt < NKTk; kt++) {
        if (kt) __syncthreads();           // prev tile's readers done
        QKV_BSTORE();
        __syncthreads();
        if (kt + 1 < NKTk) QKV_BLOAD(kt + 1);
        const int ks32b = (ks0 >> 5) + kt * 2;
        #pragma unroll
        for (int ks = 0; ks < 2; ks++) {
            const int koff = ks * 32 + lg * 8;
            bf16x8 bfr[2];
            #pragma unroll
            for (int nt = 0; nt < 2; nt++) {
                int n = nt * 16 + lm;
                bfr[nt] = *(const bf16x8*)&Bs[n * 64 + (koff ^ (((n >> 1) & 7) << 3))];
            }
            bf16x8 a0 = *(const bf16x8*)
                &fragA[(((size_t)(ks32b + ks) * 8 + rt0) * 64 + l) * 8];
            acc[0][0] = mfma16(a0, bfr[0], acc[0][0]);
            acc[0][1] = mfma16(a0, bfr[1], acc[0][1]);
            if (full) {
                bf16x8 a1 = *(const bf16x8*)
                    &fragA[(((size_t)(ks32b + ks) * 8 + rt0 + 1) * 64 + l) * 8];
                acc[1][0] = mfma16(a1, bfr[0], acc[1][0]);
                acc[1][1] = mfma16(a1, bfr[1], acc[1][1]);
            }
        }
    }

    const int wrows = full ? 32 : 16;
    const int mts = full ? 2 : 1;
    #pragma unroll
    for (int mt = 0; mt < 2; mt++) {
        if (mt >= mts) break;
        #pragma unroll
        for (int nt = 0; nt < 2; nt++)
            #pragma unroll
            for (int r = 0; r < 4; r++) {
                int grow = rowbase + w * wrows + mt * 16 + lg * 4 + r;
                part[((size_t)ksp * 128 + grow) * 6144 + col0 + nt * 16 + lm] =
                    acc[mt][nt][r];
            }
    }
    #undef QKV_BLOAD
    #undef QKV_BSTORE
}

// ------- Kernel 2: partial-sum + RMSNorm + RoPE (q, k) + v passthrough ------
template<int KS>
__global__ __launch_bounds__(256)
void k_normrope(const float* __restrict__ part,
                const float* __restrict__ cosq, const float* __restrict__ sinq,
                const float* __restrict__ cosk, const float* __restrict__ sink,
                const float* __restrict__ qnw, const float* __restrict__ knw,
                u16* __restrict__ qb, u16* __restrict__ kb,
                float* __restrict__ outk, float* __restrict__ outv,
                u16* __restrict__ vbw)
{
    int wid = blockIdx.x * 4 + (threadIdx.x >> 6);
    int lane = threadIdx.x & 63;
    if (wid < 2048) {                          // q: (h, l)
        int h = wid >> 6, lq = wid & 63;
        size_t ro = (size_t)(64 + lq) * 6144 + h * 128;
        float x1 = 0.f, x2 = 0.f;
        #pragma unroll
        for (int s = 0; s < KS; s++) {
            x1 += part[(size_t)s * 786432 + ro + lane];
            x2 += part[(size_t)s * 786432 + ro + lane + 64];
        }
        float ss = x1 * x1 + x2 * x2;
        #pragma unroll
        for (int off = 32; off; off >>= 1) ss += __shfl_xor(ss, off);
        float rms = rsqrtf(ss * (1.0f / 128.0f) + 1e-6f);
        float a = x1 * rms * qnw[lane];
        float b = x2 * rms * qnw[lane + 64];
        float c = cosq[lq * 64 + lane], s = sinq[lq * 64 + lane];
        u16* qo = qb + ((size_t)h * 64 + lq) * 128;
        qo[lane]      = f2bf((a * c - b * s) * SCALE_Q);
        qo[lane + 64] = f2bf((b * c + a * s) * SCALE_Q);
    } else if (wid < 3072) {                   // k: (kh, t)
        int rr = wid - 2048;
        int kh = rr >> 7, tt = rr & 127;
        size_t ro = (size_t)tt * 6144 + 4096 + kh * 128;
        float x1 = 0.f, x2 = 0.f;
        #pragma unroll
        for (int s = 0; s < KS; s++) {
            x1 += part[(size_t)s * 786432 + ro + lane];
            x2 += part[(size_t)s * 786432 + ro + lane + 64];
        }
        float ss = x1 * x1 + x2 * x2;
        #pragma unroll
        for (int off = 32; off; off >>= 1) ss += __shfl_xor(ss, off);
        float rms = rsqrtf(ss * (1.0f / 128.0f) + 1e-6f);
        float a = x1 * rms * knw[lane];
        float b = x2 * rms * knw[lane + 64];
        float c = cosk[tt * 64 + lane], s = sink[tt * 64 + lane];
        float o1 = a * c - b * s, o2 = b * c + a * s;
        size_t oi = ((size_t)kh * 128 + tt) * 128;
        outk[oi + lane] = o1; outk[oi + lane + 64] = o2;   // output 1 (k), f32
        kb[oi + lane] = f2bf(o1); kb[oi + lane + 64] = f2bf(o2);
    } else {                                   // v: (kh, t) partial sum only
        int rr = wid - 3072;
        int kh = rr >> 7, tt = rr & 127;
        size_t ro = (size_t)tt * 6144 + 5120 + kh * 128;
        float v1 = 0.f, v2 = 0.f;
        #pragma unroll
        for (int s = 0; s < KS; s++) {
            v1 += part[(size_t)s * 786432 + ro + lane];
            v2 += part[(size_t)s * 786432 + ro + lane + 64];
        }
        size_t oi = ((size_t)kh * 128 + tt) * 128;
        outv[oi + lane] = v1; outv[oi + lane + 64] = v2;   // output 2 (v), f32
        vbw[oi + lane] = f2bf(v1); vbw[oi + lane + 64] = f2bf(v2);
    }
}

// --------- Kernel 3: split-K flash attention (no-max online softmax) --------
// grid (NSP, 8); each block handles NBLK kv-blocks of 64 keys.
// Per-wave P buffer => NO barriers in the softmax/PV phases (wave-internal
// LDS ordering only). Vs stored with XOR-swizzled key index to kill the
// 16-way transpose-write bank conflict.
template<int NSP, int NBLK>
__global__ __launch_bounds__(256)
void k_attn(const u16* __restrict__ qb, const u16* __restrict__ kbw,
            const u16* __restrict__ vbw,
            const float* __restrict__ cacheK, const float* __restrict__ cacheV,
            u16* __restrict__ opart, float* __restrict__ lpart)
{
    const int split = blockIdx.x;
    const int kh = blockIdx.y;
    const int t = threadIdx.x;
    const int w = t >> 6, l = t & 63;
    const int lm = l & 15, lg = l >> 4;

    __shared__ __align__(16) u16 Ks[64][136];
    __shared__ __align__(16) u16 Vs[128][72];   // [d][key ^ ((d>>2)&7)<<3]
    __shared__ __align__(16) u16 Ps[4][64][40];

    const u16* qh = qb + ((size_t)(kh * 4 + w) * 64) * 128;
    bf16x8 aq[4][4];
    #pragma unroll
    for (int mt = 0; mt < 4; mt++)
        #pragma unroll
        for (int ks = 0; ks < 4; ks++)
            aq[mt][ks] = *(const bf16x8*)&qh[(size_t)(mt * 16 + lm) * 128 + ks * 32 + lg * 8];

    f32x4 accO[4][8] = {};
    float lacc[4][4] = {};
    const size_t khK = (size_t)kh * 8192 * 128;

    for (int kbi = 0; kbi < NBLK; kbi++) {
        const int key0 = split * (64 * NBLK) + kbi * 64;
        __syncthreads();                       // prior PV readers done
        #pragma unroll
        for (int it = 0; it < 8; it++) {
            int fidx = it * 256 + t;
            int row = fidx >> 5;
            int d4 = (fidx & 31) << 2;
            int srow = row ^ (((d4 >> 2) & 7) << 3);   // V key-swizzle
            int key = key0 + row;
            if (key < 4096) {
                float4 kv = *(const float4*)&cacheK[khK + (size_t)key * 128 + d4];
                ushort4 sv; sv.x = f2bf(kv.x); sv.y = f2bf(kv.y);
                sv.z = f2bf(kv.z); sv.w = f2bf(kv.w);
                *(ushort4*)&Ks[row][d4] = sv;
                float4 vv = *(const float4*)&cacheV[khK + (size_t)key * 128 + d4];
                Vs[d4 + 0][srow] = f2bf(vv.x);
                Vs[d4 + 1][srow] = f2bf(vv.y);
                Vs[d4 + 2][srow] = f2bf(vv.z);
                Vs[d4 + 3][srow] = f2bf(vv.w);
            } else {
                size_t nb = ((size_t)kh * 128 + (key - 4096)) * 128 + d4;
                ushort4 kv = *(const ushort4*)&kbw[nb];
                *(ushort4*)&Ks[row][d4] = kv;
                ushort4 vv = *(const ushort4*)&vbw[nb];
                Vs[d4 + 0][srow] = vv.x;
                Vs[d4 + 1][srow] = vv.y;
                Vs[d4 + 2][srow] = vv.z;
                Vs[d4 + 3][srow] = vv.w;
            }
        }
        __syncthreads();                       // staging complete

        f32x4 sa[4][4] = {};
        #pragma unroll
        for (int ks = 0; ks < 4; ks++) {
            bf16x8 bk[4];
            #pragma unroll
            for (int nt = 0; nt < 4; nt++)
                bk[nt] = *(const bf16x8*)&Ks[nt * 16 + lm][ks * 32 + lg * 8];
            #pragma unroll
            for (int mt = 0; mt < 4; mt++)
                #pragma unroll
                for (int nt = 0; nt < 4; nt++)
                    sa[mt][nt] = mfma16(aq[mt][ks], bk[nt], sa[mt][nt]);
        }

        // softmax + PV per 32-key half — wave-private Ps[w], no barriers
        #pragma unroll
        for (int half = 0; half < 2; half++) {
            #pragma unroll
            for (int mt = 0; mt < 4; mt++)
                #pragma unroll
                for (int nt2 = 0; nt2 < 2; nt2++)
                    #pragma unroll
                    for (int r = 0; r < 4; r++) {
                        float e = __expf(sa[mt][half * 2 + nt2][r]);
                        lacc[mt][r] += e;
                        Ps[w][mt * 16 + lg * 4 + r][nt2 * 16 + lm] = f2bf(e);
                    }
            bf16x8 pa[4];
            #pragma unroll
            for (int mt = 0; mt < 4; mt++)
                pa[mt] = *(const bf16x8*)&Ps[w][mt * 16 + lm][lg * 8];
            #pragma unroll
            for (int dt = 0; dt < 8; dt++) {
                int d = dt * 16 + lm;
                int vswz = ((d >> 2) & 7) << 3;
                bf16x8 vb8 = *(const bf16x8*)&Vs[d][(half * 32 + lg * 8) ^ vswz];
                #pragma unroll
                for (int mt = 0; mt < 4; mt++)
                    accO[mt][dt] = mfma16(pa[mt], vb8, accO[mt][dt]);
            }
        }
    }

    #pragma unroll
    for (int mt = 0; mt < 4; mt++)
        #pragma unroll
        for (int r = 0; r < 4; r++) {
            float v = lacc[mt][r];
            v += __shfl_xor(v, 1);
            v += __shfl_xor(v, 2);
            v += __shfl_xor(v, 4);
            v += __shfl_xor(v, 8);
            lacc[mt][r] = v;
        }

    const size_t base = (((size_t)kh * NSP + split) * 4 + w) * 64;
    if (lm == 0) {
        #pragma unroll
        for (int mt = 0; mt < 4; mt++)
            #pragma unroll
            for (int r = 0; r < 4; r++)
                lpart[base + mt * 16 + lg * 4 + r] = lacc[mt][r];
    }
    #pragma unroll
    for (int mt = 0; mt < 4; mt++)
        #pragma unroll
        for (int dt = 0; dt < 8; dt++)
            #pragma unroll
            for (int r = 0; r < 4; r++)
                opart[(base + mt * 16 + lg * 4 + r) * 128 + dt * 16 + lm] =
                    f2bf(accO[mt][dt][r]);
}

// ---------- Kernel 4: combine splits, normalize (vectorized u16x8) ----------
template<int NSP>
__global__ __launch_bounds__(256)
void k_combine(const u16* __restrict__ opart, const float* __restrict__ lpart,
               u16* __restrict__ obf)
{
    int idx = blockIdx.x * 256 + threadIdx.x;   // 32768 threads: (lq, col/8)
    int lq = idx >> 9;
    int c8 = (idx & 511) << 3;                  // 8-col group (within one head)
    int h = c8 >> 7, d = c8 & 127;
    int kh = h >> 2, rep = h & 3;
    float os[8] = {};
    float ls = 0.f;
    #pragma unroll 2
    for (int s = 0; s < NSP; s++) {
        size_t b = (((size_t)kh * NSP + s) * 4 + rep) * 64 + lq;
        u16x8 v = *(const u16x8*)&opart[b * 128 + d];
        #pragma unroll
        for (int j = 0; j < 8; j++) os[j] += bf2f(v[j]);
        ls += lpart[b];
    }
    float inv = 1.0f / ls;
    u16x8 o;
    #pragma unroll
    for (int j = 0; j < 8; j++) o[j] = f2bf(os[j] * inv);
    *(u16x8*)&obf[(size_t)lq * 4096 + c8] = o;
}

// ----------- Kernel 5: O projection, split-K streaming (8 splits) -----------
__global__ __launch_bounds__(256)
void k_oproj(const u16* __restrict__ obf, const float* __restrict__ Wo,
             float* __restrict__ parto)
{
    const int col0 = blockIdx.x * 32;
    const int osp = blockIdx.y;
    const int ks0 = osp * (4096 / OSPLIT);

    __shared__ __align__(16) u16 As[64][72];
    __shared__ __align__(16) u16 Bs[32 * 64];

    const int t = threadIdx.x;
    const int w = t >> 6, l = t & 63;
    const int lm = l & 15, lg = l >> 4;

    const int arow = t >> 3;               // 0..31, +32 for second half
    const int ac8 = (t & 7) << 3;
    const int bk = (t >> 3) << 1;          // even k index (k-pair)
    const int bn4 = (t & 7) << 2;

    u16x8 pa[2]; f32x4 pb[2];
    f32x4 acc[2] = {};

    #define OP_LOAD(kt_)                                                       \
    {                                                                          \
        const int kg = ks0 + (kt_) * 64;                                       \
        pa[0] = *(const u16x8*)&obf[(size_t)arow * 4096 + kg + ac8];           \
        pa[1] = *(const u16x8*)&obf[(size_t)(arow + 32) * 4096 + kg + ac8];    \
        pb[0] = *(const f32x4*)&Wo[(size_t)(kg + bk) * 4096 + col0 + bn4];     \
        pb[1] = *(const f32x4*)&Wo[(size_t)(kg + bk + 1) * 4096 + col0 + bn4]; \
    }

    #define OP_STORE()                                                         \
    {                                                                          \
        *(u16x8*)&As[arow][ac8] = pa[0];                                       \
        *(u16x8*)&As[arow + 32][ac8] = pa[1];                                  \
        _Pragma("unroll")                                                      \
        for (int j = 0; j < 4; j++) {                                          \
            int n = bn4 + j;                                                   \
            int idx = n * 64 + (bk ^ (((n >> 1) & 7) << 3));                   \
            ushort2 v2; v2.x = f2bf(pb[0][j]); v2.y = f2bf(pb[1][j]);          \
            *(ushort2*)&Bs[idx] = v2;                                          \
        }                                                                      \
    }

    OP_LOAD(0);
    #pragma unroll 1
    for (int kt = 0; kt < 4096 / OSPLIT / 64; kt++) {
        if (kt) __syncthreads();
        OP_STORE();
        __syncthreads();
        if (kt + 1 < 4096 / OSPLIT / 64) OP_LOAD(kt + 1);
        #pragma unroll
        for (int ks = 0; ks < 2; ks++) {
            const int koff = ks * 32 + lg * 8;
            bf16x8 a0 = *(const bf16x8*)&As[w * 16 + lm][koff];
            #pragma unroll
            for (int nt = 0; nt < 2; nt++) {
                int n = nt * 16 + lm;
                bf16x8 b = *(const bf16x8*)&Bs[n * 64 + (koff ^ (((n >> 1) & 7) << 3))];
                acc[nt] = mfma16(a0, b, acc[nt]);
            }
        }
    }
    #pragma unroll
    for (int nt = 0; nt < 2; nt++)
        #pragma unroll
        for (int r = 0; r < 4; r++)
            parto[((size_t)osp * 64 + w * 16 + lg * 4 + r) * 4096 +
                  col0 + nt * 16 + lm] = acc[nt][r];
    #undef OP_LOAD
    #undef OP_STORE
}

// ------------------- Kernel 6: sum O-proj split-K partials ------------------
__global__ __launch_bounds__(256)
void k_osum(const float* __restrict__ parto, float* __restrict__ out0)
{
    int idx = blockIdx.x * 256 + threadIdx.x;   // 64*4096
    float s = 0.f;
    #pragma unroll
    for (int o = 0; o < OSPLIT; o++)
        s += parto[(size_t)o * 262144 + idx];
    out0[idx] = s;
}

extern "C" void kernel_launch(void* const* d_in, const int* in_sizes, int n_in,
                              void* d_out, int out_size, void* d_ws, size_t ws_size,
                              hipStream_t stream)
{
    (void)in_sizes; (void)n_in; (void)out_size;
    const float* x      = (const float*)d_in[0];
    const float* xctx   = (const float*)d_in[1];
    const float* cosq   = (const float*)d_in[2];
    const float* sinq   = (const float*)d_in[3];
    const float* cosk   = (const float*)d_in[4];
    const float* sink   = (const float*)d_in[5];
    const float* cacheK = (const float*)d_in[6];
    const float* cacheV = (const float*)d_in[7];
    const float* Wq     = (const float*)d_in[9];
    const float* Wk     = (const float*)d_in[10];
    const float* Wv     = (const float*)d_in[11];
    const float* Wo     = (const float*)d_in[12];
    const float* qnw    = (const float*)d_in[13];
    const float* knw    = (const float*)d_in[14];

    float* out0 = (float*)d_out;               // o@Wo (64, 4096)
    float* out1 = out0 + 262144;               // k (8, 128, 128)
    float* out2 = out1 + 131072;               // v (8, 128, 128)

    // Full layout (ws >= 26,738,688; R6 proved ws >= 36.7 MB):
    //   region A [0, 25,165,824): part (8x128x6144 f32), then
    //     opart 17,301,504 + lpart 270,336 (attn 33x2), then parto 8,388,608
    //   region B at 25,165,824: fragA/qb 524,288 | kb 262,144 | vb 262,144 |
    //     obf 524,288  -> end 26,738,688.
    // Fallback (small ws): R5-proven layout, KSPLIT=4, attn (22,3).
    const bool ks8 = (ws_size >= 26738688ull);
    char* ws = (char*)d_ws;
    const size_t regB = ks8 ? 25165824ull : 12582912ull;
    const size_t lpart_off = ks8 ? 17301504ull : 11534336ull;

    float* part  = (float*)(ws + 0);           // phase 1-2
    u16*   opart = (u16*)(ws + 0);             // phase 3-4 (aliases dead part)
    float* lpart = (float*)(ws + lpart_off);
    float* parto = (float*)(ws + 0);           // phase 5-6 (aliases dead opart)
    u16*   fragA = (u16*)(ws + regB);          // aliases qb (phases 0-1)
    u16*   qb    = (u16*)(ws + regB);
    u16*   kb    = (u16*)(ws + regB + 524288);
    u16*   vb    = (u16*)(ws + regB + 786432);
    u16*   obf   = (u16*)(ws + regB + 1048576);

    k_prep<<<256, 256, 0, stream>>>(x, xctx, fragA);
    if (ks8) {
        k_qkv<8><<<dim3(192, 8), 256, 0, stream>>>(fragA, Wq, Wk, Wv, part);
        k_normrope<8><<<1024, 256, 0, stream>>>(part, cosq, sinq, cosk, sink,
                                                qnw, knw, qb, kb, out1, out2, vb);
        k_attn<33, 2><<<dim3(33, 8), 256, 0, stream>>>(qb, kb, vb, cacheK,
                                                       cacheV, opart, lpart);
        k_combine<33><<<128, 256, 0, stream>>>(opart, lpart, obf);
    } else {
        k_qkv<4><<<dim3(192, 4), 256, 0, stream>>>(fragA, Wq, Wk, Wv, part);
        k_normrope<4><<<1024, 256, 0, stream>>>(part, cosq, sinq, cosk, sink,
                                                qnw, knw, qb, kb, out1, out2, vb);
        k_attn<22, 3><<<dim3(22, 8), 256, 0, stream>>>(qb, kb, vb, cacheK,
                                                       cacheV, opart, lpart);
        k_combine<22><<<128, 256, 0, stream>>>(opart, lpart, obf);
    }
    k_oproj<<<dim3(128, OSPLIT), 256, 0, stream>>>(obf, Wo, parto);
    k_osum<<<1024, 256, 0, stream>>>(parto, out0);
}

// Round 9
// 81.944 us; speedup vs baseline: 1.2637x; 1.2637x over previous
//
#include <hip/hip_runtime.h>

typedef unsigned short u16;
typedef __bf16 bf16x8 __attribute__((ext_vector_type(8)));
typedef float f32x4 __attribute__((ext_vector_type(4)));
typedef u16 u16x8 __attribute__((ext_vector_type(8)));

#define NSPLIT 11            // attention: 4224 keys = 11 splits * 6 * 64
#define ANBLK 6
#define KSPLIT 8             // qkv GEMM K-splits
#define OSPLIT 8             // oproj K-splits
#define SCALE_Q 0.08838834764831843f   // 1/sqrt(128), folded into q

__device__ __forceinline__ u16 f2bf(float f) {
    unsigned u = __builtin_bit_cast(unsigned, f);
    u += 0x7fff + ((u >> 16) & 1);     // RNE
    return (u16)(u >> 16);
}
__device__ __forceinline__ float bf2f(u16 h) {
    unsigned u = ((unsigned)h) << 16;
    return __builtin_bit_cast(float, u);
}
__device__ __forceinline__ f32x4 mfma16(bf16x8 a, bf16x8 b, f32x4 c) {
    return __builtin_amdgcn_mfma_f32_16x16x32_bf16(a, b, c, 0, 0, 0);
}

// ------ Kernel 0: pre-pack c=[x_ctx;x] as bf16 MFMA A-fragments (1 MB) ------
__global__ __launch_bounds__(256)
void k_prep(const float* __restrict__ x, const float* __restrict__ xctx,
            u16* __restrict__ fragA)
{
    int tid = blockIdx.x * 256 + threadIdx.x;   // 65536 threads
    int row = tid >> 9;
    int k0 = (tid & 511) << 3;
    const float* src = (row < 64) ? (xctx + (size_t)row * 4096)
                                  : (x + (size_t)(row - 64) * 4096);
    f32x4 v0 = *(const f32x4*)&src[k0];
    f32x4 v1 = *(const f32x4*)&src[k0 + 4];
    u16x8 o;
    o[0] = f2bf(v0[0]); o[1] = f2bf(v0[1]); o[2] = f2bf(v0[2]); o[3] = f2bf(v0[3]);
    o[4] = f2bf(v1[0]); o[5] = f2bf(v1[1]); o[6] = f2bf(v1[2]); o[7] = f2bf(v1[3]);
    int ks32 = k0 >> 5;
    int lg = (k0 >> 3) & 3;
    int rt = row >> 4;
    int l = lg * 16 + (row & 15);
    *(u16x8*)&fragA[(((size_t)ks32 * 8 + rt) * 64 + l) * 8] = o;
}

// ---------------- Kernel 1: QKV projection, split-K streaming ---------------
template<int KS>
__global__ __launch_bounds__(256)
void k_qkv(const u16* __restrict__ fragA,
           const float* __restrict__ Wq, const float* __restrict__ Wk,
           const float* __restrict__ Wv, float* __restrict__ part)
{
    constexpr int KCk = 4096 / KS;
    constexpr int NKTk = KCk / 64;
    const int col0 = blockIdx.x * 32;
    const int ksp = blockIdx.y;
    const int ks0 = ksp * KCk;
    const float* W; int ldw, cbase, mat;
    if (col0 < 4096)      { W = Wq; ldw = 4096; cbase = col0;        mat = 0; }
    else if (col0 < 5120) { W = Wk; ldw = 1024; cbase = col0 - 4096; mat = 1; }
    else                  { W = Wv; ldw = 1024; cbase = col0 - 5120; mat = 2; }
    const bool full = (mat != 0);
    const int rowbase = full ? 0 : 64;

    __shared__ __align__(16) u16 Bs[32 * 64];

    const int t = threadIdx.x;
    const int w = t >> 6, l = t & 63;
    const int lm = l & 15, lg = l >> 4;
    const int bk = (t >> 3) << 1;
    const int bn4 = (t & 7) << 2;

    f32x4 pb[2];
    f32x4 acc[2][2] = {};
    const int rt0 = full ? (w * 2) : (4 + w);

    #define QKV_BLOAD(kt_)                                                     \
    {                                                                          \
        const int kg = ks0 + (kt_) * 64;                                       \
        pb[0] = *(const f32x4*)&W[(size_t)(kg + bk) * ldw + cbase + bn4];      \
        pb[1] = *(const f32x4*)&W[(size_t)(kg + bk + 1) * ldw + cbase + bn4];  \
    }
    #define QKV_BSTORE()                                                       \
    {                                                                          \
        _Pragma("unroll")                                                      \
        for (int j = 0; j < 4; j++) {                                          \
            int n = bn4 + j;                                                   \
            int idx = n * 64 + (bk ^ (((n >> 1) & 7) << 3));                   \
            ushort2 v2; v2.x = f2bf(pb[0][j]); v2.y = f2bf(pb[1][j]);          \
            *(ushort2*)&Bs[idx] = v2;                                          \
        }                                                                      \
    }

    QKV_BLOAD(0);
    #pragma unroll 1
    for (int kt = 0; kt < NKTk; kt++) {
        if (kt) __syncthreads();
        QKV_BSTORE();
        __syncthreads();
        if (kt + 1 < NKTk) QKV_BLOAD(kt + 1);
        const int ks32b = (ks0 >> 5) + kt * 2;
        #pragma unroll
        for (int ks = 0; ks < 2; ks++) {
            const int koff = ks * 32 + lg * 8;
            bf16x8 bfr[2];
            #pragma unroll
            for (int nt = 0; nt < 2; nt++) {
                int n = nt * 16 + lm;
                bfr[nt] = *(const bf16x8*)&Bs[n * 64 + (koff ^ (((n >> 1) & 7) << 3))];
            }
            bf16x8 a0 = *(const bf16x8*)
                &fragA[(((size_t)(ks32b + ks) * 8 + rt0) * 64 + l) * 8];
            acc[0][0] = mfma16(a0, bfr[0], acc[0][0]);
            acc[0][1] = mfma16(a0, bfr[1], acc[0][1]);
            if (full) {
                bf16x8 a1 = *(const bf16x8*)
                    &fragA[(((size_t)(ks32b + ks) * 8 + rt0 + 1) * 64 + l) * 8];
                acc[1][0] = mfma16(a1, bfr[0], acc[1][0]);
                acc[1][1] = mfma16(a1, bfr[1], acc[1][1]);
            }
        }
    }

    const int wrows = full ? 32 : 16;
    const int mts = full ? 2 : 1;
    #pragma unroll
    for (int mt = 0; mt < 2; mt++) {
        if (mt >= mts) break;
        #pragma unroll
        for (int nt = 0; nt < 2; nt++)
            #pragma unroll
            for (int r = 0; r < 4; r++) {
                int grow = rowbase + w * wrows + mt * 16 + lg * 4 + r;
                part[((size_t)ksp * 128 + grow) * 6144 + col0 + nt * 16 + lm] =
                    acc[mt][nt][r];
            }
    }
    #undef QKV_BLOAD
    #undef QKV_BSTORE
}

// ------- Kernel 2: partial-sum + RMSNorm + RoPE (q, k) + v passthrough ------
template<int KS>
__global__ __launch_bounds__(256)
void k_normrope(const float* __restrict__ part,
                const float* __restrict__ cosq, const float* __restrict__ sinq,
                const float* __restrict__ cosk, const float* __restrict__ sink,
                const float* __restrict__ qnw, const float* __restrict__ knw,
                u16* __restrict__ qb, u16* __restrict__ kb,
                float* __restrict__ outk, float* __restrict__ outv,
                u16* __restrict__ vbw)
{
    int wid = blockIdx.x * 4 + (threadIdx.x >> 6);
    int lane = threadIdx.x & 63;
    if (wid < 2048) {                          // q: (h, l)
        int h = wid >> 6, lq = wid & 63;
        size_t ro = (size_t)(64 + lq) * 6144 + h * 128;
        float x1 = 0.f, x2 = 0.f;
        #pragma unroll
        for (int s = 0; s < KS; s++) {
            x1 += part[(size_t)s * 786432 + ro + lane];
            x2 += part[(size_t)s * 786432 + ro + lane + 64];
        }
        float ss = x1 * x1 + x2 * x2;
        #pragma unroll
        for (int off = 32; off; off >>= 1) ss += __shfl_xor(ss, off);
        float rms = rsqrtf(ss * (1.0f / 128.0f) + 1e-6f);
        float a = x1 * rms * qnw[lane];
        float b = x2 * rms * qnw[lane + 64];
        float c = cosq[lq * 64 + lane], s = sinq[lq * 64 + lane];
        u16* qo = qb + ((size_t)h * 64 + lq) * 128;
        qo[lane]      = f2bf((a * c - b * s) * SCALE_Q);
        qo[lane + 64] = f2bf((b * c + a * s) * SCALE_Q);
    } else if (wid < 3072) {                   // k: (kh, t)
        int rr = wid - 2048;
        int kh = rr >> 7, tt = rr & 127;
        size_t ro = (size_t)tt * 6144 + 4096 + kh * 128;
        float x1 = 0.f, x2 = 0.f;
        #pragma unroll
        for (int s = 0; s < KS; s++) {
            x1 += part[(size_t)s * 786432 + ro + lane];
            x2 += part[(size_t)s * 786432 + ro + lane + 64];
        }
        float ss = x1 * x1 + x2 * x2;
        #pragma unroll
        for (int off = 32; off; off >>= 1) ss += __shfl_xor(ss, off);
        float rms = rsqrtf(ss * (1.0f / 128.0f) + 1e-6f);
        float a = x1 * rms * knw[lane];
        float b = x2 * rms * knw[lane + 64];
        float c = cosk[tt * 64 + lane], s = sink[tt * 64 + lane];
        float o1 = a * c - b * s, o2 = b * c + a * s;
        size_t oi = ((size_t)kh * 128 + tt) * 128;
        outk[oi + lane] = o1; outk[oi + lane + 64] = o2;   // output 1 (k), f32
        kb[oi + lane] = f2bf(o1); kb[oi + lane + 64] = f2bf(o2);
    } else {                                   // v: (kh, t) partial sum only
        int rr = wid - 3072;
        int kh = rr >> 7, tt = rr & 127;
        size_t ro = (size_t)tt * 6144 + 5120 + kh * 128;
        float v1 = 0.f, v2 = 0.f;
        #pragma unroll
        for (int s = 0; s < KS; s++) {
            v1 += part[(size_t)s * 786432 + ro + lane];
            v2 += part[(size_t)s * 786432 + ro + lane + 64];
        }
        size_t oi = ((size_t)kh * 128 + tt) * 128;
        outv[oi + lane] = v1; outv[oi + lane + 64] = v2;   // output 2 (v), f32
        vbw[oi + lane] = f2bf(v1); vbw[oi + lane + 64] = f2bf(v2);
    }
}

// ------ Kernel 2.5: build bf16 kcache[kh][4224][128] + vcacheT[kh][128][4224]
// grid 528 + 2112: first 528 blocks = V transpose tiles (kh, 64-key tile)
// via LDS; rest = streaming K copy/convert.
__global__ __launch_bounds__(256)
void k_prepkv(const float* __restrict__ cacheK, const float* __restrict__ cacheV,
              const u16* __restrict__ kb, const u16* __restrict__ vb,
              u16* __restrict__ kc, u16* __restrict__ vt)
{
    const int bx = blockIdx.x;
    const int t = threadIdx.x;
    if (bx < 528) {                            // V^T tiles
        __shared__ __align__(16) u16 Ls[64][132];
        int kh = bx / 66, tile = bx % 66;
        int key0 = tile * 64;
        #pragma unroll
        for (int it = 0; it < 8; it++) {
            int fidx = it * 256 + t;
            int row = fidx >> 5;
            int d4 = (fidx & 31) << 2;
            int key = key0 + row;
            ushort4 sv;
            if (key < 4096) {
                float4 v = *(const float4*)&cacheV[((size_t)kh * 8192 + key) * 128 + d4];
                sv.x = f2bf(v.x); sv.y = f2bf(v.y); sv.z = f2bf(v.z); sv.w = f2bf(v.w);
            } else {
                sv = *(const ushort4*)&vb[((size_t)kh * 128 + (key - 4096)) * 128 + d4];
            }
            *(ushort4*)&Ls[row][d4] = sv;
        }
        __syncthreads();
        #pragma unroll
        for (int it = 0; it < 4; it++) {       // 1024 output chunks of 8 keys
            int fidx = it * 256 + t;
            int d = fidx >> 3;
            int kc8 = (fidx & 7) << 3;
            u16x8 o;
            #pragma unroll
            for (int j = 0; j < 8; j++) o[j] = Ls[kc8 + j][d];
            *(u16x8*)&vt[((size_t)kh * 128 + d) * 4224 + key0 + kc8] = o;
        }
    } else {                                   // K copy/convert
        size_t cidx = (size_t)(bx - 528) * 256 + t;   // 540,672 chunks of 8
        int kh = (int)(cidx / 67584);
        int rem = (int)(cidx % 67584);
        int tt = rem >> 4;
        int d8 = (rem & 15) << 3;
        u16x8 o;
        if (tt < 4096) {
            const float* src = &cacheK[((size_t)kh * 8192 + tt) * 128 + d8];
            f32x4 a = *(const f32x4*)src;
            f32x4 b = *(const f32x4*)(src + 4);
            o[0] = f2bf(a[0]); o[1] = f2bf(a[1]); o[2] = f2bf(a[2]); o[3] = f2bf(a[3]);
            o[4] = f2bf(b[0]); o[5] = f2bf(b[1]); o[6] = f2bf(b[2]); o[7] = f2bf(b[3]);
        } else {
            o = *(const u16x8*)&kb[((size_t)kh * 128 + (tt - 4096)) * 128 + d8];
        }
        *(u16x8*)&kc[((size_t)kh * 4224 + tt) * 128 + d8] = o;
    }
}

// --------- Kernel 3: split-K flash attention (no-max online softmax) --------
// grid (NSPLIT, 8, 2): z = head-pair. 4 waves; wave w -> rep z*2+(w>>1),
// 32 q-rows (w&1). Branch-free bf16 staging + register prefetch of the next
// kv-block. Wave-private P => no barriers in softmax/PV.
__global__ __launch_bounds__(256)
void k_attn(const u16* __restrict__ qb, const u16* __restrict__ kcache,
            const u16* __restrict__ vcacheT,
            u16* __restrict__ opart, float* __restrict__ lpart)
{
    const int split = blockIdx.x;
    const int kh = blockIdx.y;
    const int z = blockIdx.z;
    const int t = threadIdx.x;
    const int w = t >> 6, l = t & 63;
    const int lm = l & 15, lg = l >> 4;
    const int rep = z * 2 + (w >> 1);
    const int mh = w & 1;                      // 32-row half

    __shared__ __align__(16) u16 Ks[64][136];
    __shared__ __align__(16) u16 Vs[128][72];  // [d][keychunk ^ ((d>>2)&7)]
    __shared__ __align__(16) u16 Ps[4][32][40];

    const u16* qh = qb + ((size_t)(kh * 4 + rep) * 64) * 128;
    bf16x8 aq[2][4];
    #pragma unroll
    for (int mt = 0; mt < 2; mt++)
        #pragma unroll
        for (int ks = 0; ks < 4; ks++)
            aq[mt][ks] = *(const bf16x8*)
                &qh[(size_t)(mh * 32 + mt * 16 + lm) * 128 + ks * 32 + lg * 8];

    const u16* kcb = kcache + (size_t)kh * 4224 * 128;
    const u16* vtb = vcacheT + (size_t)kh * 128 * 4224;

    // staging indices (per thread): K 4 chunks, V 4 chunks
    const int krow = t >> 4;                   // + it*16? no: fidx-based below
    const int kdc = (t & 15) << 3;             // d offset (8 elems)
    const int vd = t >> 3;                     // + it*32
    const int vkc = t & 7;                     // key chunk of 8

    u16x8 pk[4], pv[4];
    f32x4 accO[2][8] = {};
    float lacc[2][4] = {};

    #define AT_LOAD(key0_)                                                     \
    {                                                                          \
        _Pragma("unroll")                                                      \
        for (int it = 0; it < 4; it++)                                         \
            pk[it] = *(const u16x8*)&kcb[(size_t)((key0_) + it * 16 + krow) * 128 + kdc]; \
        _Pragma("unroll")                                                      \
        for (int it = 0; it < 4; it++)                                         \
            pv[it] = *(const u16x8*)&vtb[(size_t)(it * 32 + vd) * 4224 + (key0_) + vkc * 8]; \
    }
    #define AT_STORE()                                                         \
    {                                                                          \
        _Pragma("unroll")                                                      \
        for (int it = 0; it < 4; it++)                                         \
            *(u16x8*)&Ks[it * 16 + krow][kdc] = pk[it];                        \
        _Pragma("unroll")                                                      \
        for (int it = 0; it < 4; it++) {                                       \
            int d = it * 32 + vd;                                              \
            *(u16x8*)&Vs[d][(vkc ^ ((d >> 2) & 7)) << 3] = pv[it];             \
        }                                                                      \
    }

    AT_LOAD(split * (64 * ANBLK));
    #pragma unroll 1
    for (int kbi = 0; kbi < ANBLK; kbi++) {
        __syncthreads();                       // prior readers done
        AT_STORE();
        __syncthreads();                       // staging visible
        if (kbi + 1 < ANBLK) AT_LOAD(split * (64 * ANBLK) + (kbi + 1) * 64);

        f32x4 sa[2][4] = {};
        #pragma unroll
        for (int ks = 0; ks < 4; ks++) {
            bf16x8 bk[4];
            #pragma unroll
            for (int nt = 0; nt < 4; nt++)
                bk[nt] = *(const bf16x8*)&Ks[nt * 16 + lm][ks * 32 + lg * 8];
            #pragma unroll
            for (int mt = 0; mt < 2; mt++)
                #pragma unroll
                for (int nt = 0; nt < 4; nt++)
                    sa[mt][nt] = mfma16(aq[mt][ks], bk[nt], sa[mt][nt]);
        }

        #pragma unroll
        for (int half = 0; half < 2; half++) {
            #pragma unroll
            for (int mt = 0; mt < 2; mt++)
                #pragma unroll
                for (int nt2 = 0; nt2 < 2; nt2++)
                    #pragma unroll
                    for (int r = 0; r < 4; r++) {
                        float e = __expf(sa[mt][half * 2 + nt2][r]);
                        lacc[mt][r] += e;
                        Ps[w][mt * 16 + lg * 4 + r][nt2 * 16 + lm] = f2bf(e);
                    }
            bf16x8 pa[2];
            #pragma unroll
            for (int mt = 0; mt < 2; mt++)
                pa[mt] = *(const bf16x8*)&Ps[w][mt * 16 + lm][lg * 8];
            #pragma unroll
            for (int dt = 0; dt < 8; dt++) {
                int d = dt * 16 + lm;
                int vswz = ((d >> 2) & 7) << 3;
                bf16x8 vb8 = *(const bf16x8*)&Vs[d][(half * 32 + lg * 8) ^ vswz];
                #pragma unroll
                for (int mt = 0; mt < 2; mt++)
                    accO[mt][dt] = mfma16(pa[mt], vb8, accO[mt][dt]);
            }
        }
    }
    #undef AT_LOAD
    #undef AT_STORE

    #pragma unroll
    for (int mt = 0; mt < 2; mt++)
        #pragma unroll
        for (int r = 0; r < 4; r++) {
            float v = lacc[mt][r];
            v += __shfl_xor(v, 1);
            v += __shfl_xor(v, 2);
            v += __shfl_xor(v, 4);
            v += __shfl_xor(v, 8);
            lacc[mt][r] = v;
        }

    const size_t base = (((size_t)kh * NSPLIT + split) * 4 + rep) * 64 + mh * 32;
    if (lm == 0) {
        #pragma unroll
        for (int mt = 0; mt < 2; mt++)
            #pragma unroll
            for (int r = 0; r < 4; r++)
                lpart[base + mt * 16 + lg * 4 + r] = lacc[mt][r];
    }
    #pragma unroll
    for (int mt = 0; mt < 2; mt++)
        #pragma unroll
        for (int dt = 0; dt < 8; dt++)
            #pragma unroll
            for (int r = 0; r < 4; r++)
                opart[(base + mt * 16 + lg * 4 + r) * 128 + dt * 16 + lm] =
                    f2bf(accO[mt][dt][r]);
}

// ---------- Kernel 4: combine splits, normalize (vectorized u16x8) ----------
template<int NSP>
__global__ __launch_bounds__(256)
void k_combine(const u16* __restrict__ opart, const float* __restrict__ lpart,
               u16* __restrict__ obf)
{
    int idx = blockIdx.x * 256 + threadIdx.x;   // 32768 threads: (lq, col/8)
    int lq = idx >> 9;
    int c8 = (idx & 511) << 3;
    int h = c8 >> 7, d = c8 & 127;
    int kh = h >> 2, rep = h & 3;
    float os[8] = {};
    float ls = 0.f;
    #pragma unroll
    for (int s = 0; s < NSP; s++) {
        size_t b = (((size_t)kh * NSP + s) * 4 + rep) * 64 + lq;
        u16x8 v = *(const u16x8*)&opart[b * 128 + d];
        #pragma unroll
        for (int j = 0; j < 8; j++) os[j] += bf2f(v[j]);
        ls += lpart[b];
    }
    float inv = 1.0f / ls;
    u16x8 o;
    #pragma unroll
    for (int j = 0; j < 8; j++) o[j] = f2bf(os[j] * inv);
    *(u16x8*)&obf[(size_t)lq * 4096 + c8] = o;
}

// ----------- Kernel 5: O projection, split-K streaming (8 splits) -----------
__global__ __launch_bounds__(256)
void k_oproj(const u16* __restrict__ obf, const float* __restrict__ Wo,
             float* __restrict__ parto)
{
    const int col0 = blockIdx.x * 32;
    const int osp = blockIdx.y;
    const int ks0 = osp * (4096 / OSPLIT);

    __shared__ __align__(16) u16 As[64][72];
    __shared__ __align__(16) u16 Bs[32 * 64];

    const int t = threadIdx.x;
    const int w = t >> 6, l = t & 63;
    const int lm = l & 15, lg = l >> 4;

    const int arow = t >> 3;
    const int ac8 = (t & 7) << 3;
    const int bk = (t >> 3) << 1;
    const int bn4 = (t & 7) << 2;

    u16x8 pa[2]; f32x4 pb[2];
    f32x4 acc[2] = {};

    #define OP_LOAD(kt_)                                                       \
    {                                                                          \
        const int kg = ks0 + (kt_) * 64;                                       \
        pa[0] = *(const u16x8*)&obf[(size_t)arow * 4096 + kg + ac8];           \
        pa[1] = *(const u16x8*)&obf[(size_t)(arow + 32) * 4096 + kg + ac8];    \
        pb[0] = *(const f32x4*)&Wo[(size_t)(kg + bk) * 4096 + col0 + bn4];     \
        pb[1] = *(const f32x4*)&Wo[(size_t)(kg + bk + 1) * 4096 + col0 + bn4]; \
    }
    #define OP_STORE()                                                         \
    {                                                                          \
        *(u16x8*)&As[arow][ac8] = pa[0];                                       \
        *(u16x8*)&As[arow + 32][ac8] = pa[1];                                  \
        _Pragma("unroll")                                                      \
        for (int j = 0; j < 4; j++) {                                          \
            int n = bn4 + j;                                                   \
            int idx = n * 64 + (bk ^ (((n >> 1) & 7) << 3));                   \
            ushort2 v2; v2.x = f2bf(pb[0][j]); v2.y = f2bf(pb[1][j]);          \
            *(ushort2*)&Bs[idx] = v2;                                          \
        }                                                                      \
    }

    OP_LOAD(0);
    #pragma unroll 1
    for (int kt = 0; kt < 4096 / OSPLIT / 64; kt++) {
        if (kt) __syncthreads();
        OP_STORE();
        __syncthreads();
        if (kt + 1 < 4096 / OSPLIT / 64) OP_LOAD(kt + 1);
        #pragma unroll
        for (int ks = 0; ks < 2; ks++) {
            const int koff = ks * 32 + lg * 8;
            bf16x8 a0 = *(const bf16x8*)&As[w * 16 + lm][koff];
            #pragma unroll
            for (int nt = 0; nt < 2; nt++) {
                int n = nt * 16 + lm;
                bf16x8 b = *(const bf16x8*)&Bs[n * 64 + (koff ^ (((n >> 1) & 7) << 3))];
                acc[nt] = mfma16(a0, b, acc[nt]);
            }
        }
    }
    #pragma unroll
    for (int nt = 0; nt < 2; nt++)
        #pragma unroll
        for (int r = 0; r < 4; r++)
            parto[((size_t)osp * 64 + w * 16 + lg * 4 + r) * 4096 +
                  col0 + nt * 16 + lm] = acc[nt][r];
    #undef OP_LOAD
    #undef OP_STORE
}

// ------------------- Kernel 6: sum O-proj split-K partials ------------------
__global__ __launch_bounds__(256)
void k_osum(const float* __restrict__ parto, float* __restrict__ out0)
{
    int idx = blockIdx.x * 256 + threadIdx.x;
    float s = 0.f;
    #pragma unroll
    for (int o = 0; o < OSPLIT; o++)
        s += parto[(size_t)o * 262144 + idx];
    out0[idx] = s;
}

extern "C" void kernel_launch(void* const* d_in, const int* in_sizes, int n_in,
                              void* d_out, int out_size, void* d_ws, size_t ws_size,
                              hipStream_t stream)
{
    (void)in_sizes; (void)n_in; (void)out_size; (void)ws_size;
    const float* x      = (const float*)d_in[0];
    const float* xctx   = (const float*)d_in[1];
    const float* cosq   = (const float*)d_in[2];
    const float* sinq   = (const float*)d_in[3];
    const float* cosk   = (const float*)d_in[4];
    const float* sink   = (const float*)d_in[5];
    const float* cacheK = (const float*)d_in[6];
    const float* cacheV = (const float*)d_in[7];
    const float* Wq     = (const float*)d_in[9];
    const float* Wk     = (const float*)d_in[10];
    const float* Wv     = (const float*)d_in[11];
    const float* Wo     = (const float*)d_in[12];
    const float* qnw    = (const float*)d_in[13];
    const float* knw    = (const float*)d_in[14];

    float* out0 = (float*)d_out;               // o@Wo (64, 4096)
    float* out1 = out0 + 262144;               // k (8, 128, 128)
    float* out2 = out1 + 131072;               // v (8, 128, 128)

    // Layout — total 26,738,688 B, exactly the extent R7/R8 proved writable.
    // [0, 25,165,824): ph1-2 part (8x128x6144 f32); then (part dead):
    //   ph3-4: kcache [0, 8,650,752) | vcacheT [8,650,752, 17,301,504)
    //          opart  [17,301,504, 23,068,672) | lpart [23,068,672, +90,112)
    //   ph5-6: parto [0, 8,388,608) over dead kcache
    // [25,165,824, 26,738,688): region B — fragA/qb | kb | vb | obf
    char* ws = (char*)d_ws;
    float* part  = (float*)(ws + 0);
    u16*   kc    = (u16*)(ws + 0);
    u16*   vt    = (u16*)(ws + 8650752);
    u16*   opart = (u16*)(ws + 17301504);
    float* lpart = (float*)(ws + 23068672);
    float* parto = (float*)(ws + 0);
    u16*   fragA = (u16*)(ws + 25165824);
    u16*   qb    = (u16*)(ws + 25165824);
    u16*   kb    = (u16*)(ws + 25165824 + 524288);
    u16*   vb    = (u16*)(ws + 25165824 + 786432);
    u16*   obf   = (u16*)(ws + 25165824 + 1048576);

    k_prep<<<256, 256, 0, stream>>>(x, xctx, fragA);
    k_qkv<KSPLIT><<<dim3(192, KSPLIT), 256, 0, stream>>>(fragA, Wq, Wk, Wv, part);
    k_normrope<KSPLIT><<<1024, 256, 0, stream>>>(part, cosq, sinq, cosk, sink,
                                                 qnw, knw, qb, kb, out1, out2, vb);
    k_prepkv<<<2640, 256, 0, stream>>>(cacheK, cacheV, kb, vb, kc, vt);
    k_attn<<<dim3(NSPLIT, 8, 2), 256, 0, stream>>>(qb, kc, vt, opart, lpart);
    k_combine<NSPLIT><<<128, 256, 0, stream>>>(opart, lpart, obf);
    k_oproj<<<dim3(128, OSPLIT), 256, 0, stream>>>(obf, Wo, parto);
    k_osum<<<1024, 256, 0, stream>>>(parto, out0);
}

// Round 10
// 80.571 us; speedup vs baseline: 1.2853x; 1.0170x over previous
//
#include <hip/hip_runtime.h>

typedef unsigned short u16;
typedef __bf16 bf16x8 __attribute__((ext_vector_type(8)));
typedef float f32x4 __attribute__((ext_vector_type(4)));
typedef u16 u16x8 __attribute__((ext_vector_type(8)));

#define NSPLIT 11            // attention: 4224 keys = 11 splits * 6 * 64
#define ANBLK 6
#define KSPLIT 8             // qkv GEMM K-splits
#define OSPLIT 8             // oproj K-splits
#define SCALE_Q 0.08838834764831843f   // 1/sqrt(128), folded into q

__device__ __forceinline__ u16 f2bf(float f) {
    unsigned u = __builtin_bit_cast(unsigned, f);
    u += 0x7fff + ((u >> 16) & 1);     // RNE
    return (u16)(u >> 16);
}
__device__ __forceinline__ float bf2f(u16 h) {
    unsigned u = ((unsigned)h) << 16;
    return __builtin_bit_cast(float, u);
}
__device__ __forceinline__ f32x4 mfma16(bf16x8 a, bf16x8 b, f32x4 c) {
    return __builtin_amdgcn_mfma_f32_16x16x32_bf16(a, b, c, 0, 0, 0);
}

// ------ Kernel 0: pre-pack c=[x_ctx;x] as bf16 MFMA A-fragments (1 MB) ------
__global__ __launch_bounds__(256)
void k_prep(const float* __restrict__ x, const float* __restrict__ xctx,
            u16* __restrict__ fragA)
{
    int tid = blockIdx.x * 256 + threadIdx.x;   // 65536 threads
    int row = tid >> 9;
    int k0 = (tid & 511) << 3;
    const float* src = (row < 64) ? (xctx + (size_t)row * 4096)
                                  : (x + (size_t)(row - 64) * 4096);
    f32x4 v0 = *(const f32x4*)&src[k0];
    f32x4 v1 = *(const f32x4*)&src[k0 + 4];
    u16x8 o;
    o[0] = f2bf(v0[0]); o[1] = f2bf(v0[1]); o[2] = f2bf(v0[2]); o[3] = f2bf(v0[3]);
    o[4] = f2bf(v1[0]); o[5] = f2bf(v1[1]); o[6] = f2bf(v1[2]); o[7] = f2bf(v1[3]);
    int ks32 = k0 >> 5;
    int lg = (k0 >> 3) & 3;
    int rt = row >> 4;
    int l = lg * 16 + (row & 15);
    *(u16x8*)&fragA[(((size_t)ks32 * 8 + rt) * 64 + l) * 8] = o;
}

// ------- Kernel 1: QKV projection, split-K, double-buffered LDS pipeline ----
// grid (192, KS). One barrier per 64-K step; B-store of step t+1 lands after
// compute(t), so the weight load has a full compute phase to arrive.
template<int KS>
__global__ __launch_bounds__(256)
void k_qkv(const u16* __restrict__ fragA,
           const float* __restrict__ Wq, const float* __restrict__ Wk,
           const float* __restrict__ Wv, float* __restrict__ part)
{
    constexpr int KCk = 4096 / KS;
    constexpr int NKTk = KCk / 64;
    const int col0 = blockIdx.x * 32;
    const int ksp = blockIdx.y;
    const int ks0 = ksp * KCk;
    const float* W; int ldw, cbase, mat;
    if (col0 < 4096)      { W = Wq; ldw = 4096; cbase = col0;        mat = 0; }
    else if (col0 < 5120) { W = Wk; ldw = 1024; cbase = col0 - 4096; mat = 1; }
    else                  { W = Wv; ldw = 1024; cbase = col0 - 5120; mat = 2; }
    const bool full = (mat != 0);
    const int rowbase = full ? 0 : 64;

    __shared__ __align__(16) u16 Bs[2][32 * 64];   // double-buffered, 8KB

    const int t = threadIdx.x;
    const int w = t >> 6, l = t & 63;
    const int lm = l & 15, lg = l >> 4;
    const int bk = (t >> 3) << 1;
    const int bn4 = (t & 7) << 2;

    f32x4 pb[2];
    f32x4 acc[2][2] = {};
    const int rt0 = full ? (w * 2) : (4 + w);

    #define QKV_BLOAD(kt_)                                                     \
    {                                                                          \
        const int kg = ks0 + (kt_) * 64;                                       \
        pb[0] = *(const f32x4*)&W[(size_t)(kg + bk) * ldw + cbase + bn4];      \
        pb[1] = *(const f32x4*)&W[(size_t)(kg + bk + 1) * ldw + cbase + bn4];  \
    }
    #define QKV_BSTORE(buf_)                                                   \
    {                                                                          \
        _Pragma("unroll")                                                      \
        for (int j = 0; j < 4; j++) {                                          \
            int n = bn4 + j;                                                   \
            int idx = n * 64 + (bk ^ (((n >> 1) & 7) << 3));                   \
            ushort2 v2; v2.x = f2bf(pb[0][j]); v2.y = f2bf(pb[1][j]);          \
            *(ushort2*)&Bs[buf_][idx] = v2;                                    \
        }                                                                      \
    }

    QKV_BLOAD(0);
    QKV_BSTORE(0);
    __syncthreads();                   // buf0 ready
    if (NKTk > 1) QKV_BLOAD(1);
    #pragma unroll 1
    for (int kt = 0; kt < NKTk; kt++) {
        const int cur = kt & 1;
        const int ks32b = (ks0 >> 5) + kt * 2;
        #pragma unroll
        for (int ks = 0; ks < 2; ks++) {
            const int koff = ks * 32 + lg * 8;
            bf16x8 bfr[2];
            #pragma unroll
            for (int nt = 0; nt < 2; nt++) {
                int n = nt * 16 + lm;
                bfr[nt] = *(const bf16x8*)
                    &Bs[cur][n * 64 + (koff ^ (((n >> 1) & 7) << 3))];
            }
            bf16x8 a0 = *(const bf16x8*)
                &fragA[(((size_t)(ks32b + ks) * 8 + rt0) * 64 + l) * 8];
            acc[0][0] = mfma16(a0, bfr[0], acc[0][0]);
            acc[0][1] = mfma16(a0, bfr[1], acc[0][1]);
            if (full) {
                bf16x8 a1 = *(const bf16x8*)
                    &fragA[(((size_t)(ks32b + ks) * 8 + rt0 + 1) * 64 + l) * 8];
                acc[1][0] = mfma16(a1, bfr[0], acc[1][0]);
                acc[1][1] = mfma16(a1, bfr[1], acc[1][1]);
            }
        }
        if (kt + 1 < NKTk) {
            QKV_BSTORE(cur ^ 1);       // store next tile (no reader conflict)
            if (kt + 2 < NKTk) QKV_BLOAD(kt + 2);
            __syncthreads();           // next buffer visible for kt+1
        }
    }

    const int wrows = full ? 32 : 16;
    const int mts = full ? 2 : 1;
    #pragma unroll
    for (int mt = 0; mt < 2; mt++) {
        if (mt >= mts) break;
        #pragma unroll
        for (int nt = 0; nt < 2; nt++)
            #pragma unroll
            for (int r = 0; r < 4; r++) {
                int grow = rowbase + w * wrows + mt * 16 + lg * 4 + r;
                part[((size_t)ksp * 128 + grow) * 6144 + col0 + nt * 16 + lm] =
                    acc[mt][nt][r];
            }
    }
    #undef QKV_BLOAD
    #undef QKV_BSTORE
}

// ------- Kernel 2: partial-sum + RMSNorm + RoPE (q, k) + v passthrough ------
template<int KS>
__global__ __launch_bounds__(256)
void k_normrope(const float* __restrict__ part,
                const float* __restrict__ cosq, const float* __restrict__ sinq,
                const float* __restrict__ cosk, const float* __restrict__ sink,
                const float* __restrict__ qnw, const float* __restrict__ knw,
                u16* __restrict__ qb, u16* __restrict__ kb,
                float* __restrict__ outk, float* __restrict__ outv,
                u16* __restrict__ vbw)
{
    int wid = blockIdx.x * 4 + (threadIdx.x >> 6);
    int lane = threadIdx.x & 63;
    if (wid < 2048) {                          // q: (h, l)
        int h = wid >> 6, lq = wid & 63;
        size_t ro = (size_t)(64 + lq) * 6144 + h * 128;
        float x1 = 0.f, x2 = 0.f;
        #pragma unroll
        for (int s = 0; s < KS; s++) {
            x1 += part[(size_t)s * 786432 + ro + lane];
            x2 += part[(size_t)s * 786432 + ro + lane + 64];
        }
        float ss = x1 * x1 + x2 * x2;
        #pragma unroll
        for (int off = 32; off; off >>= 1) ss += __shfl_xor(ss, off);
        float rms = rsqrtf(ss * (1.0f / 128.0f) + 1e-6f);
        float a = x1 * rms * qnw[lane];
        float b = x2 * rms * qnw[lane + 64];
        float c = cosq[lq * 64 + lane], s = sinq[lq * 64 + lane];
        u16* qo = qb + ((size_t)h * 64 + lq) * 128;
        qo[lane]      = f2bf((a * c - b * s) * SCALE_Q);
        qo[lane + 64] = f2bf((b * c + a * s) * SCALE_Q);
    } else if (wid < 3072) {                   // k: (kh, t)
        int rr = wid - 2048;
        int kh = rr >> 7, tt = rr & 127;
        size_t ro = (size_t)tt * 6144 + 4096 + kh * 128;
        float x1 = 0.f, x2 = 0.f;
        #pragma unroll
        for (int s = 0; s < KS; s++) {
            x1 += part[(size_t)s * 786432 + ro + lane];
            x2 += part[(size_t)s * 786432 + ro + lane + 64];
        }
        float ss = x1 * x1 + x2 * x2;
        #pragma unroll
        for (int off = 32; off; off >>= 1) ss += __shfl_xor(ss, off);
        float rms = rsqrtf(ss * (1.0f / 128.0f) + 1e-6f);
        float a = x1 * rms * knw[lane];
        float b = x2 * rms * knw[lane + 64];
        float c = cosk[tt * 64 + lane], s = sink[tt * 64 + lane];
        float o1 = a * c - b * s, o2 = b * c + a * s;
        size_t oi = ((size_t)kh * 128 + tt) * 128;
        outk[oi + lane] = o1; outk[oi + lane + 64] = o2;   // output 1 (k), f32
        kb[oi + lane] = f2bf(o1); kb[oi + lane + 64] = f2bf(o2);
    } else {                                   // v: (kh, t) partial sum only
        int rr = wid - 3072;
        int kh = rr >> 7, tt = rr & 127;
        size_t ro = (size_t)tt * 6144 + 5120 + kh * 128;
        float v1 = 0.f, v2 = 0.f;
        #pragma unroll
        for (int s = 0; s < KS; s++) {
            v1 += part[(size_t)s * 786432 + ro + lane];
            v2 += part[(size_t)s * 786432 + ro + lane + 64];
        }
        size_t oi = ((size_t)kh * 128 + tt) * 128;
        outv[oi + lane] = v1; outv[oi + lane + 64] = v2;   // output 2 (v), f32
        vbw[oi + lane] = f2bf(v1); vbw[oi + lane + 64] = f2bf(v2);
    }
}

// ------ Kernel 2.5: build bf16 kcache[kh][4224][128] + vcacheT[kh][128][4224]
__global__ __launch_bounds__(256)
void k_prepkv(const float* __restrict__ cacheK, const float* __restrict__ cacheV,
              const u16* __restrict__ kb, const u16* __restrict__ vb,
              u16* __restrict__ kc, u16* __restrict__ vt)
{
    const int bx = blockIdx.x;
    const int t = threadIdx.x;
    if (bx < 528) {                            // V^T tiles
        __shared__ __align__(16) u16 Ls[64][132];
        int kh = bx / 66, tile = bx % 66;
        int key0 = tile * 64;
        #pragma unroll
        for (int it = 0; it < 8; it++) {
            int fidx = it * 256 + t;
            int row = fidx >> 5;
            int d4 = (fidx & 31) << 2;
            int key = key0 + row;
            ushort4 sv;
            if (key < 4096) {
                float4 v = *(const float4*)&cacheV[((size_t)kh * 8192 + key) * 128 + d4];
                sv.x = f2bf(v.x); sv.y = f2bf(v.y); sv.z = f2bf(v.z); sv.w = f2bf(v.w);
            } else {
                sv = *(const ushort4*)&vb[((size_t)kh * 128 + (key - 4096)) * 128 + d4];
            }
            *(ushort4*)&Ls[row][d4] = sv;
        }
        __syncthreads();
        #pragma unroll
        for (int it = 0; it < 4; it++) {
            int fidx = it * 256 + t;
            int d = fidx >> 3;
            int kc8 = (fidx & 7) << 3;
            u16x8 o;
            #pragma unroll
            for (int j = 0; j < 8; j++) o[j] = Ls[kc8 + j][d];
            *(u16x8*)&vt[((size_t)kh * 128 + d) * 4224 + key0 + kc8] = o;
        }
    } else {                                   // K copy/convert
        size_t cidx = (size_t)(bx - 528) * 256 + t;
        int kh = (int)(cidx / 67584);
        int rem = (int)(cidx % 67584);
        int tt = rem >> 4;
        int d8 = (rem & 15) << 3;
        u16x8 o;
        if (tt < 4096) {
            const float* src = &cacheK[((size_t)kh * 8192 + tt) * 128 + d8];
            f32x4 a = *(const f32x4*)src;
            f32x4 b = *(const f32x4*)(src + 4);
            o[0] = f2bf(a[0]); o[1] = f2bf(a[1]); o[2] = f2bf(a[2]); o[3] = f2bf(a[3]);
            o[4] = f2bf(b[0]); o[5] = f2bf(b[1]); o[6] = f2bf(b[2]); o[7] = f2bf(b[3]);
        } else {
            o = *(const u16x8*)&kb[((size_t)kh * 128 + (tt - 4096)) * 128 + d8];
        }
        *(u16x8*)&kc[((size_t)kh * 4224 + tt) * 128 + d8] = o;
    }
}

// --------- Kernel 3: split-K flash attention (no-max online softmax) --------
__global__ __launch_bounds__(256)
void k_attn(const u16* __restrict__ qb, const u16* __restrict__ kcache,
            const u16* __restrict__ vcacheT,
            u16* __restrict__ opart, float* __restrict__ lpart)
{
    const int split = blockIdx.x;
    const int kh = blockIdx.y;
    const int z = blockIdx.z;
    const int t = threadIdx.x;
    const int w = t >> 6, l = t & 63;
    const int lm = l & 15, lg = l >> 4;
    const int rep = z * 2 + (w >> 1);
    const int mh = w & 1;

    __shared__ __align__(16) u16 Ks[64][136];
    __shared__ __align__(16) u16 Vs[128][72];
    __shared__ __align__(16) u16 Ps[4][32][40];

    const u16* qh = qb + ((size_t)(kh * 4 + rep) * 64) * 128;
    bf16x8 aq[2][4];
    #pragma unroll
    for (int mt = 0; mt < 2; mt++)
        #pragma unroll
        for (int ks = 0; ks < 4; ks++)
            aq[mt][ks] = *(const bf16x8*)
                &qh[(size_t)(mh * 32 + mt * 16 + lm) * 128 + ks * 32 + lg * 8];

    const u16* kcb = kcache + (size_t)kh * 4224 * 128;
    const u16* vtb = vcacheT + (size_t)kh * 128 * 4224;

    const int krow = t >> 4;
    const int kdc = (t & 15) << 3;
    const int vd = t >> 3;
    const int vkc = t & 7;

    u16x8 pk[4], pv[4];
    f32x4 accO[2][8] = {};
    float lacc[2][4] = {};

    #define AT_LOAD(key0_)                                                     \
    {                                                                          \
        _Pragma("unroll")                                                      \
        for (int it = 0; it < 4; it++)                                         \
            pk[it] = *(const u16x8*)&kcb[(size_t)((key0_) + it * 16 + krow) * 128 + kdc]; \
        _Pragma("unroll")                                                      \
        for (int it = 0; it < 4; it++)                                         \
            pv[it] = *(const u16x8*)&vtb[(size_t)(it * 32 + vd) * 4224 + (key0_) + vkc * 8]; \
    }
    #define AT_STORE()                                                         \
    {                                                                          \
        _Pragma("unroll")                                                      \
        for (int it = 0; it < 4; it++)                                         \
            *(u16x8*)&Ks[it * 16 + krow][kdc] = pk[it];                        \
        _Pragma("unroll")                                                      \
        for (int it = 0; it < 4; it++) {                                       \
            int d = it * 32 + vd;                                              \
            *(u16x8*)&Vs[d][(vkc ^ ((d >> 2) & 7)) << 3] = pv[it];             \
        }                                                                      \
    }

    AT_LOAD(split * (64 * ANBLK));
    #pragma unroll 1
    for (int kbi = 0; kbi < ANBLK; kbi++) {
        __syncthreads();
        AT_STORE();
        __syncthreads();
        if (kbi + 1 < ANBLK) AT_LOAD(split * (64 * ANBLK) + (kbi + 1) * 64);

        f32x4 sa[2][4] = {};
        #pragma unroll
        for (int ks = 0; ks < 4; ks++) {
            bf16x8 bk[4];
            #pragma unroll
            for (int nt = 0; nt < 4; nt++)
                bk[nt] = *(const bf16x8*)&Ks[nt * 16 + lm][ks * 32 + lg * 8];
            #pragma unroll
            for (int mt = 0; mt < 2; mt++)
                #pragma unroll
                for (int nt = 0; nt < 4; nt++)
                    sa[mt][nt] = mfma16(aq[mt][ks], bk[nt], sa[mt][nt]);
        }

        #pragma unroll
        for (int half = 0; half < 2; half++) {
            #pragma unroll
            for (int mt = 0; mt < 2; mt++)
                #pragma unroll
                for (int nt2 = 0; nt2 < 2; nt2++)
                    #pragma unroll
                    for (int r = 0; r < 4; r++) {
                        float e = __expf(sa[mt][half * 2 + nt2][r]);
                        lacc[mt][r] += e;
                        Ps[w][mt * 16 + lg * 4 + r][nt2 * 16 + lm] = f2bf(e);
                    }
            bf16x8 pa[2];
            #pragma unroll
            for (int mt = 0; mt < 2; mt++)
                pa[mt] = *(const bf16x8*)&Ps[w][mt * 16 + lm][lg * 8];
            #pragma unroll
            for (int dt = 0; dt < 8; dt++) {
                int d = dt * 16 + lm;
                int vswz = ((d >> 2) & 7) << 3;
                bf16x8 vb8 = *(const bf16x8*)&Vs[d][(half * 32 + lg * 8) ^ vswz];
                #pragma unroll
                for (int mt = 0; mt < 2; mt++)
                    accO[mt][dt] = mfma16(pa[mt], vb8, accO[mt][dt]);
            }
        }
    }
    #undef AT_LOAD
    #undef AT_STORE

    #pragma unroll
    for (int mt = 0; mt < 2; mt++)
        #pragma unroll
        for (int r = 0; r < 4; r++) {
            float v = lacc[mt][r];
            v += __shfl_xor(v, 1);
            v += __shfl_xor(v, 2);
            v += __shfl_xor(v, 4);
            v += __shfl_xor(v, 8);
            lacc[mt][r] = v;
        }

    const size_t base = (((size_t)kh * NSPLIT + split) * 4 + rep) * 64 + mh * 32;
    if (lm == 0) {
        #pragma unroll
        for (int mt = 0; mt < 2; mt++)
            #pragma unroll
            for (int r = 0; r < 4; r++)
                lpart[base + mt * 16 + lg * 4 + r] = lacc[mt][r];
    }
    #pragma unroll
    for (int mt = 0; mt < 2; mt++)
        #pragma unroll
        for (int dt = 0; dt < 8; dt++)
            #pragma unroll
            for (int r = 0; r < 4; r++)
                opart[(base + mt * 16 + lg * 4 + r) * 128 + dt * 16 + lm] =
                    f2bf(accO[mt][dt][r]);
}

// ---------- Kernel 4: combine splits, normalize (vectorized u16x8) ----------
template<int NSP>
__global__ __launch_bounds__(256)
void k_combine(const u16* __restrict__ opart, const float* __restrict__ lpart,
               u16* __restrict__ obf)
{
    int idx = blockIdx.x * 256 + threadIdx.x;
    int lq = idx >> 9;
    int c8 = (idx & 511) << 3;
    int h = c8 >> 7, d = c8 & 127;
    int kh = h >> 2, rep = h & 3;
    float os[8] = {};
    float ls = 0.f;
    #pragma unroll
    for (int s = 0; s < NSP; s++) {
        size_t b = (((size_t)kh * NSP + s) * 4 + rep) * 64 + lq;
        u16x8 v = *(const u16x8*)&opart[b * 128 + d];
        #pragma unroll
        for (int j = 0; j < 8; j++) os[j] += bf2f(v[j]);
        ls += lpart[b];
    }
    float inv = 1.0f / ls;
    u16x8 o;
    #pragma unroll
    for (int j = 0; j < 8; j++) o[j] = f2bf(os[j] * inv);
    *(u16x8*)&obf[(size_t)lq * 4096 + c8] = o;
}

// ------- Kernel 5: O projection, split-K, double-buffered LDS pipeline ------
__global__ __launch_bounds__(256)
void k_oproj(const u16* __restrict__ obf, const float* __restrict__ Wo,
             float* __restrict__ parto)
{
    constexpr int NKT = 4096 / OSPLIT / 64;    // 8
    const int col0 = blockIdx.x * 32;
    const int osp = blockIdx.y;
    const int ks0 = osp * (4096 / OSPLIT);

    __shared__ __align__(16) u16 As[2][64][72];
    __shared__ __align__(16) u16 Bs[2][32 * 64];

    const int t = threadIdx.x;
    const int w = t >> 6, l = t & 63;
    const int lm = l & 15, lg = l >> 4;

    const int arow = t >> 3;
    const int ac8 = (t & 7) << 3;
    const int bk = (t >> 3) << 1;
    const int bn4 = (t & 7) << 2;

    u16x8 pa[2]; f32x4 pb[2];
    f32x4 acc[2] = {};

    #define OP_LOAD(kt_)                                                       \
    {                                                                          \
        const int kg = ks0 + (kt_) * 64;                                       \
        pa[0] = *(const u16x8*)&obf[(size_t)arow * 4096 + kg + ac8];           \
        pa[1] = *(const u16x8*)&obf[(size_t)(arow + 32) * 4096 + kg + ac8];    \
        pb[0] = *(const f32x4*)&Wo[(size_t)(kg + bk) * 4096 + col0 + bn4];     \
        pb[1] = *(const f32x4*)&Wo[(size_t)(kg + bk + 1) * 4096 + col0 + bn4]; \
    }
    #define OP_STORE(buf_)                                                     \
    {                                                                          \
        *(u16x8*)&As[buf_][arow][ac8] = pa[0];                                 \
        *(u16x8*)&As[buf_][arow + 32][ac8] = pa[1];                            \
        _Pragma("unroll")                                                      \
        for (int j = 0; j < 4; j++) {                                          \
            int n = bn4 + j;                                                   \
            int idx = n * 64 + (bk ^ (((n >> 1) & 7) << 3));                   \
            ushort2 v2; v2.x = f2bf(pb[0][j]); v2.y = f2bf(pb[1][j]);          \
            *(ushort2*)&Bs[buf_][idx] = v2;                                    \
        }                                                                      \
    }

    OP_LOAD(0);
    OP_STORE(0);
    __syncthreads();
    OP_LOAD(1);
    #pragma unroll 1
    for (int kt = 0; kt < NKT; kt++) {
        const int cur = kt & 1;
        #pragma unroll
        for (int ks = 0; ks < 2; ks++) {
            const int koff = ks * 32 + lg * 8;
            bf16x8 a0 = *(const bf16x8*)&As[cur][w * 16 + lm][koff];
            #pragma unroll
            for (int nt = 0; nt < 2; nt++) {
                int n = nt * 16 + lm;
                bf16x8 b = *(const bf16x8*)
                    &Bs[cur][n * 64 + (koff ^ (((n >> 1) & 7) << 3))];
                acc[nt] = mfma16(a0, b, acc[nt]);
            }
        }
        if (kt + 1 < NKT) {
            OP_STORE(cur ^ 1);
            if (kt + 2 < NKT) OP_LOAD(kt + 2);
            __syncthreads();
        }
    }
    #pragma unroll
    for (int nt = 0; nt < 2; nt++)
        #pragma unroll
        for (int r = 0; r < 4; r++)
            parto[((size_t)osp * 64 + w * 16 + lg * 4 + r) * 4096 +
                  col0 + nt * 16 + lm] = acc[nt][r];
    #undef OP_LOAD
    #undef OP_STORE
}

// ------------------- Kernel 6: sum O-proj split-K partials ------------------
__global__ __launch_bounds__(256)
void k_osum(const float* __restrict__ parto, float* __restrict__ out0)
{
    int idx = blockIdx.x * 256 + threadIdx.x;
    float s = 0.f;
    #pragma unroll
    for (int o = 0; o < OSPLIT; o++)
        s += parto[(size_t)o * 262144 + idx];
    out0[idx] = s;
}

extern "C" void kernel_launch(void* const* d_in, const int* in_sizes, int n_in,
                              void* d_out, int out_size, void* d_ws, size_t ws_size,
                              hipStream_t stream)
{
    (void)in_sizes; (void)n_in; (void)out_size; (void)ws_size;
    const float* x      = (const float*)d_in[0];
    const float* xctx   = (const float*)d_in[1];
    const float* cosq   = (const float*)d_in[2];
    const float* sinq   = (const float*)d_in[3];
    const float* cosk   = (const float*)d_in[4];
    const float* sink   = (const float*)d_in[5];
    const float* cacheK = (const float*)d_in[6];
    const float* cacheV = (const float*)d_in[7];
    const float* Wq     = (const float*)d_in[9];
    const float* Wk     = (const float*)d_in[10];
    const float* Wv     = (const float*)d_in[11];
    const float* Wo     = (const float*)d_in[12];
    const float* qnw    = (const float*)d_in[13];
    const float* knw    = (const float*)d_in[14];

    float* out0 = (float*)d_out;               // o@Wo (64, 4096)
    float* out1 = out0 + 262144;               // k (8, 128, 128)
    float* out2 = out1 + 131072;               // v (8, 128, 128)

    // Layout — total 26,738,688 B (extent proven writable in R7-R9).
    char* ws = (char*)d_ws;
    float* part  = (float*)(ws + 0);
    u16*   kc    = (u16*)(ws + 0);
    u16*   vt    = (u16*)(ws + 8650752);
    u16*   opart = (u16*)(ws + 17301504);
    float* lpart = (float*)(ws + 23068672);
    float* parto = (float*)(ws + 0);
    u16*   fragA = (u16*)(ws + 25165824);
    u16*   qb    = (u16*)(ws + 25165824);
    u16*   kb    = (u16*)(ws + 25165824 + 524288);
    u16*   vb    = (u16*)(ws + 25165824 + 786432);
    u16*   obf   = (u16*)(ws + 25165824 + 1048576);

    k_prep<<<256, 256, 0, stream>>>(x, xctx, fragA);
    k_qkv<KSPLIT><<<dim3(192, KSPLIT), 256, 0, stream>>>(fragA, Wq, Wk, Wv, part);
    k_normrope<KSPLIT><<<1024, 256, 0, stream>>>(part, cosq, sinq, cosk, sink,
                                                 qnw, knw, qb, kb, out1, out2, vb);
    k_prepkv<<<2640, 256, 0, stream>>>(cacheK, cacheV, kb, vb, kc, vt);
    k_attn<<<dim3(NSPLIT, 8, 2), 256, 0, stream>>>(qb, kc, vt, opart, lpart);
    k_combine<NSPLIT><<<128, 256, 0, stream>>>(opart, lpart, obf);
    k_oproj<<<dim3(128, OSPLIT), 256, 0, stream>>>(obf, Wo, parto);
    k_osum<<<1024, 256, 0, stream>>>(parto, out0);
}

// Round 11
// 77.274 us; speedup vs baseline: 1.3401x; 1.0427x over previous
//
#include <hip/hip_runtime.h>

typedef unsigned short u16;
typedef __bf16 bf16x8 __attribute__((ext_vector_type(8)));
typedef float f32x4 __attribute__((ext_vector_type(4)));
typedef u16 u16x8 __attribute__((ext_vector_type(8)));

#define NSPLIT 11            // attention: 4224 keys = 11 splits * 6 * 64
#define ANBLK 6
#define KSPLIT 4             // qkv GEMM K-splits (depth now from reg ring)
#define OSPLIT 8             // oproj K-splits
#define SCALE_Q 0.08838834764831843f   // 1/sqrt(128), folded into q

__device__ __forceinline__ u16 f2bf(float f) {
    unsigned u = __builtin_bit_cast(unsigned, f);
    u += 0x7fff + ((u >> 16) & 1);     // RNE
    return (u16)(u >> 16);
}
__device__ __forceinline__ float bf2f(u16 h) {
    unsigned u = ((unsigned)h) << 16;
    return __builtin_bit_cast(float, u);
}
__device__ __forceinline__ f32x4 mfma16(bf16x8 a, bf16x8 b, f32x4 c) {
    return __builtin_amdgcn_mfma_f32_16x16x32_bf16(a, b, c, 0, 0, 0);
}

// ------ Kernel 0: pre-pack c=[x_ctx;x] as bf16 MFMA A-fragments (1 MB) ------
__global__ __launch_bounds__(256)
void k_prep(const float* __restrict__ x, const float* __restrict__ xctx,
            u16* __restrict__ fragA)
{
    int tid = blockIdx.x * 256 + threadIdx.x;   // 65536 threads
    int row = tid >> 9;
    int k0 = (tid & 511) << 3;
    const float* src = (row < 64) ? (xctx + (size_t)row * 4096)
                                  : (x + (size_t)(row - 64) * 4096);
    f32x4 v0 = *(const f32x4*)&src[k0];
    f32x4 v1 = *(const f32x4*)&src[k0 + 4];
    u16x8 o;
    o[0] = f2bf(v0[0]); o[1] = f2bf(v0[1]); o[2] = f2bf(v0[2]); o[3] = f2bf(v0[3]);
    o[4] = f2bf(v1[0]); o[5] = f2bf(v1[1]); o[6] = f2bf(v1[2]); o[7] = f2bf(v1[3]);
    int ks32 = k0 >> 5;
    int lg = (k0 >> 3) & 3;
    int rt = row >> 4;
    int l = lg * 16 + (row & 15);
    *(u16x8*)&fragA[(((size_t)ks32 * 8 + rt) * 64 + l) * 8] = o;
}

// ------ Kernel 1: QKV projection, split-K, 4-deep register-ring pipeline ----
// grid (192, KS). W loads issued 4 steps ahead into pb[4][2]; fragA fragments
// 1 step ahead into af[2][4]. Fully unrolled so ring indices are static.
template<int KS>
__global__ __launch_bounds__(256)
void k_qkv(const u16* __restrict__ fragA,
           const float* __restrict__ Wq, const float* __restrict__ Wk,
           const float* __restrict__ Wv, float* __restrict__ part)
{
    constexpr int KCk = 4096 / KS;
    constexpr int NKT = KCk / 64;
    const int col0 = blockIdx.x * 32;
    const int ksp = blockIdx.y;
    const int ks0 = ksp * KCk;
    const float* W; int ldw, cbase, mat;
    if (col0 < 4096)      { W = Wq; ldw = 4096; cbase = col0;        mat = 0; }
    else if (col0 < 5120) { W = Wk; ldw = 1024; cbase = col0 - 4096; mat = 1; }
    else                  { W = Wv; ldw = 1024; cbase = col0 - 5120; mat = 2; }
    const bool full = (mat != 0);
    const int rowbase = full ? 0 : 64;

    __shared__ __align__(16) u16 Bs[2][32 * 64];   // double-buffered, 8KB

    const int t = threadIdx.x;
    const int w = t >> 6, l = t & 63;
    const int lm = l & 15, lg = l >> 4;
    const int bk = (t >> 3) << 1;
    const int bn4 = (t & 7) << 2;

    f32x4 pb[4][2];                    // W ring, 4 steps deep
    bf16x8 af[2][4];                   // fragA double buffer
    f32x4 acc[2][2] = {};
    const int rt0 = full ? (w * 2) : (4 + w);

    #define QKV_BLOAD(slot_, kt_)                                              \
    {                                                                          \
        const int kg = ks0 + (kt_) * 64;                                       \
        pb[slot_][0] = *(const f32x4*)&W[(size_t)(kg + bk) * ldw + cbase + bn4]; \
        pb[slot_][1] = *(const f32x4*)&W[(size_t)(kg + bk + 1) * ldw + cbase + bn4]; \
    }
    #define QKV_BSTORE(buf_, slot_)                                            \
    {                                                                          \
        _Pragma("unroll")                                                      \
        for (int j = 0; j < 4; j++) {                                          \
            int n = bn4 + j;                                                   \
            int idx = n * 64 + (bk ^ (((n >> 1) & 7) << 3));                   \
            ushort2 v2; v2.x = f2bf(pb[slot_][0][j]); v2.y = f2bf(pb[slot_][1][j]); \
            *(ushort2*)&Bs[buf_][idx] = v2;                                    \
        }                                                                      \
    }
    #define QKV_ALOAD(p_, kt_)                                                 \
    {                                                                          \
        const int kb32 = (ks0 >> 5) + (kt_) * 2;                               \
        af[p_][0] = *(const bf16x8*)&fragA[(((size_t)kb32 * 8 + rt0) * 64 + l) * 8]; \
        af[p_][1] = *(const bf16x8*)&fragA[(((size_t)(kb32 + 1) * 8 + rt0) * 64 + l) * 8]; \
        if (full) {                                                            \
            af[p_][2] = *(const bf16x8*)&fragA[(((size_t)kb32 * 8 + rt0 + 1) * 64 + l) * 8]; \
            af[p_][3] = *(const bf16x8*)&fragA[(((size_t)(kb32 + 1) * 8 + rt0 + 1) * 64 + l) * 8]; \
        }                                                                      \
    }

    QKV_BLOAD(0, 0);
    QKV_BLOAD(1, 1);
    QKV_BLOAD(2, 2);
    QKV_BLOAD(3, 3);
    QKV_ALOAD(0, 0);
    QKV_BSTORE(0, 0);
    __syncthreads();                   // buf0 ready

    #pragma unroll
    for (int kt = 0; kt < NKT; kt++) {
        const int cur = kt & 1;
        if (kt + 4 < NKT) QKV_BLOAD(kt & 3, kt + 4);     // refill freed slot
        if (kt + 1 < NKT) QKV_ALOAD((kt + 1) & 1, kt + 1);
        if (kt + 1 < NKT) QKV_BSTORE(cur ^ 1, (kt + 1) & 3);
        #pragma unroll
        for (int ks = 0; ks < 2; ks++) {
            const int koff = ks * 32 + lg * 8;
            bf16x8 bfr[2];
            #pragma unroll
            for (int nt = 0; nt < 2; nt++) {
                int n = nt * 16 + lm;
                bfr[nt] = *(const bf16x8*)
                    &Bs[cur][n * 64 + (koff ^ (((n >> 1) & 7) << 3))];
            }
            acc[0][0] = mfma16(af[cur][ks], bfr[0], acc[0][0]);
            acc[0][1] = mfma16(af[cur][ks], bfr[1], acc[0][1]);
            if (full) {
                acc[1][0] = mfma16(af[cur][2 + ks], bfr[0], acc[1][0]);
                acc[1][1] = mfma16(af[cur][2 + ks], bfr[1], acc[1][1]);
            }
        }
        if (kt + 1 < NKT) __syncthreads();   // next buffer visible
    }

    const int wrows = full ? 32 : 16;
    const int mts = full ? 2 : 1;
    #pragma unroll
    for (int mt = 0; mt < 2; mt++) {
        if (mt >= mts) break;
        #pragma unroll
        for (int nt = 0; nt < 2; nt++)
            #pragma unroll
            for (int r = 0; r < 4; r++) {
                int grow = rowbase + w * wrows + mt * 16 + lg * 4 + r;
                part[((size_t)ksp * 128 + grow) * 6144 + col0 + nt * 16 + lm] =
                    acc[mt][nt][r];
            }
    }
    #undef QKV_BLOAD
    #undef QKV_BSTORE
    #undef QKV_ALOAD
}

// ------- Kernel 2: partial-sum + RMSNorm + RoPE (q, k) + v passthrough ------
template<int KS>
__global__ __launch_bounds__(256)
void k_normrope(const float* __restrict__ part,
                const float* __restrict__ cosq, const float* __restrict__ sinq,
                const float* __restrict__ cosk, const float* __restrict__ sink,
                const float* __restrict__ qnw, const float* __restrict__ knw,
                u16* __restrict__ qb, u16* __restrict__ kb,
                float* __restrict__ outk, float* __restrict__ outv,
                u16* __restrict__ vbw)
{
    int wid = blockIdx.x * 4 + (threadIdx.x >> 6);
    int lane = threadIdx.x & 63;
    if (wid < 2048) {                          // q: (h, l)
        int h = wid >> 6, lq = wid & 63;
        size_t ro = (size_t)(64 + lq) * 6144 + h * 128;
        float x1 = 0.f, x2 = 0.f;
        #pragma unroll
        for (int s = 0; s < KS; s++) {
            x1 += part[(size_t)s * 786432 + ro + lane];
            x2 += part[(size_t)s * 786432 + ro + lane + 64];
        }
        float ss = x1 * x1 + x2 * x2;
        #pragma unroll
        for (int off = 32; off; off >>= 1) ss += __shfl_xor(ss, off);
        float rms = rsqrtf(ss * (1.0f / 128.0f) + 1e-6f);
        float a = x1 * rms * qnw[lane];
        float b = x2 * rms * qnw[lane + 64];
        float c = cosq[lq * 64 + lane], s = sinq[lq * 64 + lane];
        u16* qo = qb + ((size_t)h * 64 + lq) * 128;
        qo[lane]      = f2bf((a * c - b * s) * SCALE_Q);
        qo[lane + 64] = f2bf((b * c + a * s) * SCALE_Q);
    } else if (wid < 3072) {                   // k: (kh, t)
        int rr = wid - 2048;
        int kh = rr >> 7, tt = rr & 127;
        size_t ro = (size_t)tt * 6144 + 4096 + kh * 128;
        float x1 = 0.f, x2 = 0.f;
        #pragma unroll
        for (int s = 0; s < KS; s++) {
            x1 += part[(size_t)s * 786432 + ro + lane];
            x2 += part[(size_t)s * 786432 + ro + lane + 64];
        }
        float ss = x1 * x1 + x2 * x2;
        #pragma unroll
        for (int off = 32; off; off >>= 1) ss += __shfl_xor(ss, off);
        float rms = rsqrtf(ss * (1.0f / 128.0f) + 1e-6f);
        float a = x1 * rms * knw[lane];
        float b = x2 * rms * knw[lane + 64];
        float c = cosk[tt * 64 + lane], s = sink[tt * 64 + lane];
        float o1 = a * c - b * s, o2 = b * c + a * s;
        size_t oi = ((size_t)kh * 128 + tt) * 128;
        outk[oi + lane] = o1; outk[oi + lane + 64] = o2;   // output 1 (k), f32
        kb[oi + lane] = f2bf(o1); kb[oi + lane + 64] = f2bf(o2);
    } else {                                   // v: (kh, t) partial sum only
        int rr = wid - 3072;
        int kh = rr >> 7, tt = rr & 127;
        size_t ro = (size_t)tt * 6144 + 5120 + kh * 128;
        float v1 = 0.f, v2 = 0.f;
        #pragma unroll
        for (int s = 0; s < KS; s++) {
            v1 += part[(size_t)s * 786432 + ro + lane];
            v2 += part[(size_t)s * 786432 + ro + lane + 64];
        }
        size_t oi = ((size_t)kh * 128 + tt) * 128;
        outv[oi + lane] = v1; outv[oi + lane + 64] = v2;   // output 2 (v), f32
        vbw[oi + lane] = f2bf(v1); vbw[oi + lane + 64] = f2bf(v2);
    }
}

// ------ Kernel 2.5: build bf16 kcache[kh][4224][128] + vcacheT[kh][128][4224]
__global__ __launch_bounds__(256)
void k_prepkv(const float* __restrict__ cacheK, const float* __restrict__ cacheV,
              const u16* __restrict__ kb, const u16* __restrict__ vb,
              u16* __restrict__ kc, u16* __restrict__ vt)
{
    const int bx = blockIdx.x;
    const int t = threadIdx.x;
    if (bx < 528) {                            // V^T tiles
        __shared__ __align__(16) u16 Ls[64][132];
        int kh = bx / 66, tile = bx % 66;
        int key0 = tile * 64;
        #pragma unroll
        for (int it = 0; it < 8; it++) {
            int fidx = it * 256 + t;
            int row = fidx >> 5;
            int d4 = (fidx & 31) << 2;
            int key = key0 + row;
            ushort4 sv;
            if (key < 4096) {
                float4 v = *(const float4*)&cacheV[((size_t)kh * 8192 + key) * 128 + d4];
                sv.x = f2bf(v.x); sv.y = f2bf(v.y); sv.z = f2bf(v.z); sv.w = f2bf(v.w);
            } else {
                sv = *(const ushort4*)&vb[((size_t)kh * 128 + (key - 4096)) * 128 + d4];
            }
            *(ushort4*)&Ls[row][d4] = sv;
        }
        __syncthreads();
        #pragma unroll
        for (int it = 0; it < 4; it++) {
            int fidx = it * 256 + t;
            int d = fidx >> 3;
            int kc8 = (fidx & 7) << 3;
            u16x8 o;
            #pragma unroll
            for (int j = 0; j < 8; j++) o[j] = Ls[kc8 + j][d];
            *(u16x8*)&vt[((size_t)kh * 128 + d) * 4224 + key0 + kc8] = o;
        }
    } else {                                   // K copy/convert
        size_t cidx = (size_t)(bx - 528) * 256 + t;
        int kh = (int)(cidx / 67584);
        int rem = (int)(cidx % 67584);
        int tt = rem >> 4;
        int d8 = (rem & 15) << 3;
        u16x8 o;
        if (tt < 4096) {
            const float* src = &cacheK[((size_t)kh * 8192 + tt) * 128 + d8];
            f32x4 a = *(const f32x4*)src;
            f32x4 b = *(const f32x4*)(src + 4);
            o[0] = f2bf(a[0]); o[1] = f2bf(a[1]); o[2] = f2bf(a[2]); o[3] = f2bf(a[3]);
            o[4] = f2bf(b[0]); o[5] = f2bf(b[1]); o[6] = f2bf(b[2]); o[7] = f2bf(b[3]);
        } else {
            o = *(const u16x8*)&kb[((size_t)kh * 128 + (tt - 4096)) * 128 + d8];
        }
        *(u16x8*)&kc[((size_t)kh * 4224 + tt) * 128 + d8] = o;
    }
}

// --------- Kernel 3: split-K flash attention (no-max online softmax) --------
__global__ __launch_bounds__(256)
void k_attn(const u16* __restrict__ qb, const u16* __restrict__ kcache,
            const u16* __restrict__ vcacheT,
            u16* __restrict__ opart, float* __restrict__ lpart)
{
    const int split = blockIdx.x;
    const int kh = blockIdx.y;
    const int z = blockIdx.z;
    const int t = threadIdx.x;
    const int w = t >> 6, l = t & 63;
    const int lm = l & 15, lg = l >> 4;
    const int rep = z * 2 + (w >> 1);
    const int mh = w & 1;

    __shared__ __align__(16) u16 Ks[64][136];
    __shared__ __align__(16) u16 Vs[128][72];
    __shared__ __align__(16) u16 Ps[4][32][40];

    const u16* qh = qb + ((size_t)(kh * 4 + rep) * 64) * 128;
    bf16x8 aq[2][4];
    #pragma unroll
    for (int mt = 0; mt < 2; mt++)
        #pragma unroll
        for (int ks = 0; ks < 4; ks++)
            aq[mt][ks] = *(const bf16x8*)
                &qh[(size_t)(mh * 32 + mt * 16 + lm) * 128 + ks * 32 + lg * 8];

    const u16* kcb = kcache + (size_t)kh * 4224 * 128;
    const u16* vtb = vcacheT + (size_t)kh * 128 * 4224;

    const int krow = t >> 4;
    const int kdc = (t & 15) << 3;
    const int vd = t >> 3;
    const int vkc = t & 7;

    u16x8 pk[4], pv[4];
    f32x4 accO[2][8] = {};
    float lacc[2][4] = {};

    #define AT_LOAD(key0_)                                                     \
    {                                                                          \
        _Pragma("unroll")                                                      \
        for (int it = 0; it < 4; it++)                                         \
            pk[it] = *(const u16x8*)&kcb[(size_t)((key0_) + it * 16 + krow) * 128 + kdc]; \
        _Pragma("unroll")                                                      \
        for (int it = 0; it < 4; it++)                                         \
            pv[it] = *(const u16x8*)&vtb[(size_t)(it * 32 + vd) * 4224 + (key0_) + vkc * 8]; \
    }
    #define AT_STORE()                                                         \
    {                                                                          \
        _Pragma("unroll")                                                      \
        for (int it = 0; it < 4; it++)                                         \
            *(u16x8*)&Ks[it * 16 + krow][kdc] = pk[it];                        \
        _Pragma("unroll")                                                      \
        for (int it = 0; it < 4; it++) {                                       \
            int d = it * 32 + vd;                                              \
            *(u16x8*)&Vs[d][(vkc ^ ((d >> 2) & 7)) << 3] = pv[it];             \
        }                                                                      \
    }

    AT_LOAD(split * (64 * ANBLK));
    #pragma unroll 1
    for (int kbi = 0; kbi < ANBLK; kbi++) {
        __syncthreads();
        AT_STORE();
        __syncthreads();
        if (kbi + 1 < ANBLK) AT_LOAD(split * (64 * ANBLK) + (kbi + 1) * 64);

        f32x4 sa[2][4] = {};
        #pragma unroll
        for (int ks = 0; ks < 4; ks++) {
            bf16x8 bk[4];
            #pragma unroll
            for (int nt = 0; nt < 4; nt++)
                bk[nt] = *(const bf16x8*)&Ks[nt * 16 + lm][ks * 32 + lg * 8];
            #pragma unroll
            for (int mt = 0; mt < 2; mt++)
                #pragma unroll
                for (int nt = 0; nt < 4; nt++)
                    sa[mt][nt] = mfma16(aq[mt][ks], bk[nt], sa[mt][nt]);
        }

        #pragma unroll
        for (int half = 0; half < 2; half++) {
            #pragma unroll
            for (int mt = 0; mt < 2; mt++)
                #pragma unroll
                for (int nt2 = 0; nt2 < 2; nt2++)
                    #pragma unroll
                    for (int r = 0; r < 4; r++) {
                        float e = __expf(sa[mt][half * 2 + nt2][r]);
                        lacc[mt][r] += e;
                        Ps[w][mt * 16 + lg * 4 + r][nt2 * 16 + lm] = f2bf(e);
                    }
            bf16x8 pa[2];
            #pragma unroll
            for (int mt = 0; mt < 2; mt++)
                pa[mt] = *(const bf16x8*)&Ps[w][mt * 16 + lm][lg * 8];
            #pragma unroll
            for (int dt = 0; dt < 8; dt++) {
                int d = dt * 16 + lm;
                int vswz = ((d >> 2) & 7) << 3;
                bf16x8 vb8 = *(const bf16x8*)&Vs[d][(half * 32 + lg * 8) ^ vswz];
                #pragma unroll
                for (int mt = 0; mt < 2; mt++)
                    accO[mt][dt] = mfma16(pa[mt], vb8, accO[mt][dt]);
            }
        }
    }
    #undef AT_LOAD
    #undef AT_STORE

    #pragma unroll
    for (int mt = 0; mt < 2; mt++)
        #pragma unroll
        for (int r = 0; r < 4; r++) {
            float v = lacc[mt][r];
            v += __shfl_xor(v, 1);
            v += __shfl_xor(v, 2);
            v += __shfl_xor(v, 4);
            v += __shfl_xor(v, 8);
            lacc[mt][r] = v;
        }

    const size_t base = (((size_t)kh * NSPLIT + split) * 4 + rep) * 64 + mh * 32;
    if (lm == 0) {
        #pragma unroll
        for (int mt = 0; mt < 2; mt++)
            #pragma unroll
            for (int r = 0; r < 4; r++)
                lpart[base + mt * 16 + lg * 4 + r] = lacc[mt][r];
    }
    #pragma unroll
    for (int mt = 0; mt < 2; mt++)
        #pragma unroll
        for (int dt = 0; dt < 8; dt++)
            #pragma unroll
            for (int r = 0; r < 4; r++)
                opart[(base + mt * 16 + lg * 4 + r) * 128 + dt * 16 + lm] =
                    f2bf(accO[mt][dt][r]);
}

// ---------- Kernel 4: combine splits, normalize (vectorized u16x8) ----------
template<int NSP>
__global__ __launch_bounds__(256)
void k_combine(const u16* __restrict__ opart, const float* __restrict__ lpart,
               u16* __restrict__ obf)
{
    int idx = blockIdx.x * 256 + threadIdx.x;
    int lq = idx >> 9;
    int c8 = (idx & 511) << 3;
    int h = c8 >> 7, d = c8 & 127;
    int kh = h >> 2, rep = h & 3;
    float os[8] = {};
    float ls = 0.f;
    #pragma unroll
    for (int s = 0; s < NSP; s++) {
        size_t b = (((size_t)kh * NSP + s) * 4 + rep) * 64 + lq;
        u16x8 v = *(const u16x8*)&opart[b * 128 + d];
        #pragma unroll
        for (int j = 0; j < 8; j++) os[j] += bf2f(v[j]);
        ls += lpart[b];
    }
    float inv = 1.0f / ls;
    u16x8 o;
    #pragma unroll
    for (int j = 0; j < 8; j++) o[j] = f2bf(os[j] * inv);
    *(u16x8*)&obf[(size_t)lq * 4096 + c8] = o;
}

// ------ Kernel 5: O projection, split-K, 4-deep register-ring pipeline ------
__global__ __launch_bounds__(256)
void k_oproj(const u16* __restrict__ obf, const float* __restrict__ Wo,
             float* __restrict__ parto)
{
    constexpr int NKT = 4096 / OSPLIT / 64;    // 8
    const int col0 = blockIdx.x * 32;
    const int osp = blockIdx.y;
    const int ks0 = osp * (4096 / OSPLIT);

    __shared__ __align__(16) u16 As[2][64][72];
    __shared__ __align__(16) u16 Bs[2][32 * 64];

    const int t = threadIdx.x;
    const int w = t >> 6, l = t & 63;
    const int lm = l & 15, lg = l >> 4;

    const int arow = t >> 3;
    const int ac8 = (t & 7) << 3;
    const int bk = (t >> 3) << 1;
    const int bn4 = (t & 7) << 2;

    u16x8 pa[4][2];
    f32x4 pb[4][2];
    f32x4 acc[2] = {};

    #define OP_LOAD(slot_, kt_)                                                \
    {                                                                          \
        const int kg = ks0 + (kt_) * 64;                                       \
        pa[slot_][0] = *(const u16x8*)&obf[(size_t)arow * 4096 + kg + ac8];    \
        pa[slot_][1] = *(const u16x8*)&obf[(size_t)(arow + 32) * 4096 + kg + ac8]; \
        pb[slot_][0] = *(const f32x4*)&Wo[(size_t)(kg + bk) * 4096 + col0 + bn4]; \
        pb[slot_][1] = *(const f32x4*)&Wo[(size_t)(kg + bk + 1) * 4096 + col0 + bn4]; \
    }
    #define OP_STORE(buf_, slot_)                                              \
    {                                                                          \
        *(u16x8*)&As[buf_][arow][ac8] = pa[slot_][0];                          \
        *(u16x8*)&As[buf_][arow + 32][ac8] = pa[slot_][1];                     \
        _Pragma("unroll")                                                      \
        for (int j = 0; j < 4; j++) {                                          \
            int n = bn4 + j;                                                   \
            int idx = n * 64 + (bk ^ (((n >> 1) & 7) << 3));                   \
            ushort2 v2; v2.x = f2bf(pb[slot_][0][j]); v2.y = f2bf(pb[slot_][1][j]); \
            *(ushort2*)&Bs[buf_][idx] = v2;                                    \
        }                                                                      \
    }

    OP_LOAD(0, 0);
    OP_LOAD(1, 1);
    OP_LOAD(2, 2);
    OP_LOAD(3, 3);
    OP_STORE(0, 0);
    __syncthreads();

    #pragma unroll
    for (int kt = 0; kt < NKT; kt++) {
        const int cur = kt & 1;
        if (kt + 4 < NKT) OP_LOAD(kt & 3, kt + 4);
        if (kt + 1 < NKT) OP_STORE(cur ^ 1, (kt + 1) & 3);
        #pragma unroll
        for (int ks = 0; ks < 2; ks++) {
            const int koff = ks * 32 + lg * 8;
            bf16x8 a0 = *(const bf16x8*)&As[cur][w * 16 + lm][koff];
            #pragma unroll
            for (int nt = 0; nt < 2; nt++) {
                int n = nt * 16 + lm;
                bf16x8 b = *(const bf16x8*)
                    &Bs[cur][n * 64 + (koff ^ (((n >> 1) & 7) << 3))];
                acc[nt] = mfma16(a0, b, acc[nt]);
            }
        }
        if (kt + 1 < NKT) __syncthreads();
    }
    #pragma unroll
    for (int nt = 0; nt < 2; nt++)
        #pragma unroll
        for (int r = 0; r < 4; r++)
            parto[((size_t)osp * 64 + w * 16 + lg * 4 + r) * 4096 +
                  col0 + nt * 16 + lm] = acc[nt][r];
    #undef OP_LOAD
    #undef OP_STORE
}

// ------------------- Kernel 6: sum O-proj split-K partials ------------------
__global__ __launch_bounds__(256)
void k_osum(const float* __restrict__ parto, float* __restrict__ out0)
{
    int idx = blockIdx.x * 256 + threadIdx.x;
    float s = 0.f;
    #pragma unroll
    for (int o = 0; o < OSPLIT; o++)
        s += parto[(size_t)o * 262144 + idx];
    out0[idx] = s;
}

extern "C" void kernel_launch(void* const* d_in, const int* in_sizes, int n_in,
                              void* d_out, int out_size, void* d_ws, size_t ws_size,
                              hipStream_t stream)
{
    (void)in_sizes; (void)n_in; (void)out_size; (void)ws_size;
    const float* x      = (const float*)d_in[0];
    const float* xctx   = (const float*)d_in[1];
    const float* cosq   = (const float*)d_in[2];
    const float* sinq   = (const float*)d_in[3];
    const float* cosk   = (const float*)d_in[4];
    const float* sink   = (const float*)d_in[5];
    const float* cacheK = (const float*)d_in[6];
    const float* cacheV = (const float*)d_in[7];
    const float* Wq     = (const float*)d_in[9];
    const float* Wk     = (const float*)d_in[10];
    const float* Wv     = (const float*)d_in[11];
    const float* Wo     = (const float*)d_in[12];
    const float* qnw    = (const float*)d_in[13];
    const float* knw    = (const float*)d_in[14];

    float* out0 = (float*)d_out;               // o@Wo (64, 4096)
    float* out1 = out0 + 262144;               // k (8, 128, 128)
    float* out2 = out1 + 131072;               // v (8, 128, 128)

    // Layout — total 26,738,688 B (extent proven writable in R7-R10).
    char* ws = (char*)d_ws;
    float* part  = (float*)(ws + 0);           // 4 x 128 x 6144 f32 = 12.6 MB
    u16*   kc    = (u16*)(ws + 0);
    u16*   vt    = (u16*)(ws + 8650752);
    u16*   opart = (u16*)(ws + 17301504);
    float* lpart = (float*)(ws + 23068672);
    float* parto = (float*)(ws + 0);
    u16*   fragA = (u16*)(ws + 25165824);
    u16*   qb    = (u16*)(ws + 25165824);
    u16*   kb    = (u16*)(ws + 25165824 + 524288);
    u16*   vb    = (u16*)(ws + 25165824 + 786432);
    u16*   obf   = (u16*)(ws + 25165824 + 1048576);

    k_prep<<<256, 256, 0, stream>>>(x, xctx, fragA);
    k_qkv<KSPLIT><<<dim3(192, KSPLIT), 256, 0, stream>>>(fragA, Wq, Wk, Wv, part);
    k_normrope<KSPLIT><<<1024, 256, 0, stream>>>(part, cosq, sinq, cosk, sink,
                                                 qnw, knw, qb, kb, out1, out2, vb);
    k_prepkv<<<2640, 256, 0, stream>>>(cacheK, cacheV, kb, vb, kc, vt);
    k_attn<<<dim3(NSPLIT, 8, 2), 256, 0, stream>>>(qb, kc, vt, opart, lpart);
    k_combine<NSPLIT><<<128, 256, 0, stream>>>(opart, lpart, obf);
    k_oproj<<<dim3(128, OSPLIT), 256, 0, stream>>>(obf, Wo, parto);
    k_osum<<<1024, 256, 0, stream>>>(parto, out0);
}